// Round 2
// baseline (245.805 us; speedup 1.0000x reference)
//
#include <hip/hip_runtime.h>
#include <hip/hip_bf16.h>
#include <cstdint>

#define T_SEQ 4096
#define C_EMB 1024
#define NH    16
#define HS    64
#define WIN   256
#define SINKSZ 4

typedef short  short8  __attribute__((ext_vector_type(8)));
typedef short  short4v __attribute__((ext_vector_type(4)));
typedef float  f32x4   __attribute__((ext_vector_type(4)));
typedef unsigned short u16;

__device__ __forceinline__ u16 f2bf(float f) {
    uint32_t u = __builtin_bit_cast(uint32_t, f);
    u = u + 0x7fffu + ((u >> 16) & 1u);   // RNE
    return (u16)(u >> 16);
}

__device__ __forceinline__ void gload_lds16(const void* g, void* l) {
    __builtin_amdgcn_global_load_lds(
        (const __attribute__((address_space(1))) uint32_t*)g,
        (__attribute__((address_space(3))) uint32_t*)l, 16, 0, 0);
}

// ---------------- f32 -> bf16 convert (vectorized) ----------------
__global__ __launch_bounds__(256) void cvt_f32_bf16(const float* __restrict__ src,
                                                    u16* __restrict__ dst, int n4) {
    int i = blockIdx.x * 256 + threadIdx.x;
    if (i >= n4) return;
    float4 v = ((const float4*)src)[i];
    ushort4 o;
    o.x = f2bf(v.x); o.y = f2bf(v.y); o.z = f2bf(v.z); o.w = f2bf(v.w);
    ((ushort4*)dst)[i] = o;
}

// ---------------- bf16 GEMM: C = A @ Bt^T + bias ----------------
// A: (M,K) bf16 row-major.  Bt: (N,K) bf16 row-major (i.e. weight (out,in) — torch Linear).
// OUT_F32=0: bf16 out (N-major rows), OUT_F32=1: f32 out.
template<int OUT_F32>
__global__ __launch_bounds__(256) void gemm_bt(const u16* __restrict__ A,
                                               const u16* __restrict__ Bt,
                                               const float* __restrict__ bias,
                                               void* __restrict__ Cout,
                                               int M, int N, int K) {
    __shared__ u16 As[128 * 32];
    __shared__ u16 Bs[128 * 32];
    const int tid = threadIdx.x;
    const int l  = tid & 63;
    const int wid = tid >> 6;
    const int lr = l & 15, g = l >> 4;
    const int m0 = blockIdx.x * 128, n0 = blockIdx.y * 128;
    const int wm = (wid >> 1) * 64, wn = (wid & 1) * 64;

    f32x4 acc[4][4];
#pragma unroll
    for (int m = 0; m < 4; ++m)
#pragma unroll
        for (int n = 0; n < 4; ++n)
            acc[m][n] = (f32x4){0.f, 0.f, 0.f, 0.f};

    for (int kt = 0; kt < K; kt += 32) {
#pragma unroll
        for (int j = 0; j < 2; ++j) {
            int e = j * 256 + tid;          // 512 chunks of 8 bf16 cover 128x32
            int row = e >> 2, col = (e & 3) << 3;
            gload_lds16(A  + (size_t)(m0 + row) * K + kt + col, As + e * 8);
            gload_lds16(Bt + (size_t)(n0 + row) * K + kt + col, Bs + e * 8);
        }
        __syncthreads();   // compiler drains vmcnt(0) before barrier -> LDS valid
        short8 af[4], bf[4];
#pragma unroll
        for (int m = 0; m < 4; ++m)
            af[m] = *(const short8*)(As + (wm + m * 16 + lr) * 32 + g * 8);
#pragma unroll
        for (int n = 0; n < 4; ++n)
            bf[n] = *(const short8*)(Bs + (wn + n * 16 + lr) * 32 + g * 8);
#pragma unroll
        for (int m = 0; m < 4; ++m)
#pragma unroll
            for (int n = 0; n < 4; ++n)
                acc[m][n] = __builtin_amdgcn_mfma_f32_16x16x32_bf16(af[m], bf[n], acc[m][n], 0, 0, 0);
        __syncthreads();   // before next stage overwrites LDS
    }

    // epilogue: C row = m0+wm+16m+4g+r, col = n0+wn+16n+lr
#pragma unroll
    for (int n = 0; n < 4; ++n) {
        int col = n0 + wn + n * 16 + lr;
        float b = bias[col];
#pragma unroll
        for (int m = 0; m < 4; ++m) {
            int rowb = m0 + wm + m * 16 + g * 4;
#pragma unroll
            for (int r = 0; r < 4; ++r) {
                float v = acc[m][n][r] + b;
                if (OUT_F32) ((float*)Cout)[(size_t)(rowb + r) * N + col] = v;
                else         ((u16*)Cout)[(size_t)(rowb + r) * N + col] = f2bf(v);
            }
        }
    }
}

// ---------------- bf16 transpose (T,C) -> (C,T) ----------------
__global__ __launch_bounds__(256) void transpose_bf16(const u16* __restrict__ src,
                                                      u16* __restrict__ dst) {
    __shared__ u16 tile[64][72];   // pad to 72 for aligned b128 reads
    int t0 = blockIdx.x * 64, c0 = blockIdx.y * 64;
    int tid = threadIdx.x;
    int rp = tid >> 3, cp = (tid & 7) * 8;
#pragma unroll
    for (int p = 0; p < 2; ++p) {
        int row = p * 32 + rp;
        short8 v = *(const short8*)(src + (size_t)(t0 + row) * C_EMB + c0 + cp);
#pragma unroll
        for (int j = 0; j < 8; ++j) tile[cp + j][row] = (u16)v[j];
    }
    __syncthreads();
#pragma unroll
    for (int p = 0; p < 2; ++p) {
        int row = p * 32 + rp;   // c-local
        short8 v = *(const short8*)(&tile[row][cp]);
        *(short8*)(dst + (size_t)(c0 + row) * T_SEQ + t0 + cp) = v;
    }
}

// ---------------- windowed flash attention ----------------
// Q,K: (T,C) bf16 per-head contiguous hs.  Vt: (C,T) bf16 (row = h*64+d).
// Yo: (T,C) bf16.  One block = 1 head x 64 q-rows; 4 waves x 16 q-rows.
__global__ __launch_bounds__(256) void attn_win(const u16* __restrict__ Q,
                                                const u16* __restrict__ Kk,
                                                const u16* __restrict__ Vt,
                                                u16* __restrict__ Yo) {
    __shared__ u16 P[4][16][32];     // per-wave P^T staging (q x key)
    const int tid = threadIdx.x;
    const int l = tid & 63, wid = tid >> 6;
    const int lr = l & 15, g = l >> 4;
    const int h  = blockIdx.x >> 6;
    const int qs = (blockIdx.x & 63) * 64;
    const int q0 = qs + wid * 16;
    const int qrow = q0 + lr;
    const float scale = 0.125f;      // 1/sqrt(64)

    short8 qf[2];
#pragma unroll
    for (int u = 0; u < 2; ++u)
        qf[u] = *(const short8*)(Q + (size_t)qrow * C_EMB + h * HS + u * 32 + g * 8);

    f32x4 acc[4];
#pragma unroll
    for (int dt = 0; dt < 4; ++dt) acc[dt] = (f32x4){0.f, 0.f, 0.f, 0.f};
    float mrun = -1e30f, lsum = 0.f;

    int ks = qs - (WIN - 1);
    if (ks < 0) ks = 0; else ks &= ~31;
    const int nch = ((qs + 64) - ks) >> 5;
    const bool sinkch = (ks > 0);
    const int total = nch + (sinkch ? 1 : 0);

    for (int ci = 0; ci < total; ++ci) {
        int kb = sinkch ? (ci == 0 ? 0 : ks + (ci - 1) * 32) : ks + ci * 32;

        // S^T = K . Q^T for 32 keys (2 halves of 16)
        f32x4 s[2];
#pragma unroll
        for (int u2 = 0; u2 < 2; ++u2) {
            const u16* kr = Kk + (size_t)(kb + u2 * 16 + lr) * C_EMB + h * HS;
            short8 kf0 = *(const short8*)(kr + g * 8);
            short8 kf1 = *(const short8*)(kr + 32 + g * 8);
            f32x4 z = (f32x4){0.f, 0.f, 0.f, 0.f};
            z = __builtin_amdgcn_mfma_f32_16x16x32_bf16(kf0, qf[0], z, 0, 0, 0);
            z = __builtin_amdgcn_mfma_f32_16x16x32_bf16(kf1, qf[1], z, 0, 0, 0);
            s[u2] = z;
        }
        // mask + scale; row = key-local = 4g+r, col = q = lr
        float pmax = -1e30f;
#pragma unroll
        for (int u2 = 0; u2 < 2; ++u2)
#pragma unroll
            for (int r = 0; r < 4; ++r) {
                int key = kb + u2 * 16 + g * 4 + r;
                bool ok = (key <= qrow) && ((key + (WIN - 1) >= qrow) || (key < SINKSZ));
                float sv = ok ? s[u2][r] * scale : -1e30f;
                s[u2][r] = sv;
                pmax = fmaxf(pmax, sv);
            }
        pmax = fmaxf(pmax, __shfl_xor(pmax, 16, 64));
        pmax = fmaxf(pmax, __shfl_xor(pmax, 32, 64));
        float mnew = fmaxf(mrun, pmax);
        float fsc = __expf(mrun - mnew);
        float psum = 0.f;
#pragma unroll
        for (int u2 = 0; u2 < 2; ++u2)
#pragma unroll
            for (int r = 0; r < 4; ++r) {
                float p = __expf(s[u2][r] - mnew);
                s[u2][r] = p;
                psum += p;
            }
        psum += __shfl_xor(psum, 16, 64);
        psum += __shfl_xor(psum, 32, 64);
        lsum = lsum * fsc + psum;
        mrun = mnew;
#pragma unroll
        for (int dt = 0; dt < 4; ++dt) {
#pragma unroll
            for (int r = 0; r < 4; ++r) acc[dt][r] *= fsc;
        }
        // write P^T (q x 32 keys) to LDS as bf16
#pragma unroll
        for (int u2 = 0; u2 < 2; ++u2) {
            short4v pw;
#pragma unroll
            for (int r = 0; r < 4; ++r) pw[r] = (short)f2bf(s[u2][r]);
            *(short4v*)(&P[wid][lr][u2 * 16 + g * 4]) = pw;
        }
        __syncthreads();
        // PV: y^T[d][q] += V^T[d,k] . P^T[k,q]
#pragma unroll
        for (int dt = 0; dt < 4; ++dt) {
            short8 vf = *(const short8*)(Vt + (size_t)(h * HS + dt * 16 + lr) * T_SEQ + kb + g * 8);
            short8 pf = *(const short8*)(&P[wid][lr][g * 8]);
            acc[dt] = __builtin_amdgcn_mfma_f32_16x16x32_bf16(vf, pf, acc[dt], 0, 0, 0);
        }
        __syncthreads();
    }

    float inv = 1.f / lsum;
#pragma unroll
    for (int dt = 0; dt < 4; ++dt) {
        short4v w;
#pragma unroll
        for (int r = 0; r < 4; ++r) w[r] = (short)f2bf(acc[dt][r] * inv);
        *(short4v*)(Yo + (size_t)qrow * C_EMB + h * HS + dt * 16 + g * 4) = w;
    }
}

extern "C" void kernel_launch(void* const* d_in, const int* in_sizes, int n_in,
                              void* d_out, int out_size, void* d_ws, size_t ws_size,
                              hipStream_t stream) {
    const float* x   = (const float*)d_in[0];
    const float* q_w = (const float*)d_in[1];
    const float* q_b = (const float*)d_in[2];
    const float* k_w = (const float*)d_in[3];
    const float* k_b = (const float*)d_in[4];
    const float* v_w = (const float*)d_in[5];
    const float* v_b = (const float*)d_in[6];
    const float* o_w = (const float*)d_in[7];
    const float* o_b = (const float*)d_in[8];
    float* out = (float*)d_out;

    char* ws = (char*)d_ws;
    const size_t SZ_TC = (size_t)T_SEQ * C_EMB * 2;   // 8 MiB
    const size_t SZ_W  = (size_t)C_EMB * C_EMB * 2;   // 2 MiB
    u16* xb   = (u16*)(ws);                 ws += SZ_TC;
    u16* wqb  = (u16*)(ws);                 ws += SZ_W;
    u16* wkb  = (u16*)(ws);                 ws += SZ_W;
    u16* wvb  = (u16*)(ws);                 ws += SZ_W;
    u16* wob  = (u16*)(ws);                 ws += SZ_W;
    u16* qbuf = (u16*)(ws);                 ws += SZ_TC;
    u16* kbuf = (u16*)(ws);                 ws += SZ_TC;
    u16* vtmp = (u16*)(ws);                 ws += SZ_TC;
    u16* vt   = (u16*)(ws);                 ws += SZ_TC;
    u16* yatt = (u16*)(ws);                 ws += SZ_TC;

    const int nTC4 = T_SEQ * C_EMB / 4, nW4 = C_EMB * C_EMB / 4;
    cvt_f32_bf16<<<(nTC4 + 255) / 256, 256, 0, stream>>>(x,   xb,  nTC4);
    cvt_f32_bf16<<<(nW4 + 255) / 256, 256, 0, stream>>>(q_w, wqb, nW4);
    cvt_f32_bf16<<<(nW4 + 255) / 256, 256, 0, stream>>>(k_w, wkb, nW4);
    cvt_f32_bf16<<<(nW4 + 255) / 256, 256, 0, stream>>>(v_w, wvb, nW4);
    cvt_f32_bf16<<<(nW4 + 255) / 256, 256, 0, stream>>>(o_w, wob, nW4);

    dim3 ggrid(T_SEQ / 128, C_EMB / 128);
    gemm_bt<0><<<ggrid, 256, 0, stream>>>(xb, wqb, q_b, qbuf, T_SEQ, C_EMB, C_EMB);
    gemm_bt<0><<<ggrid, 256, 0, stream>>>(xb, wkb, k_b, kbuf, T_SEQ, C_EMB, C_EMB);
    gemm_bt<0><<<ggrid, 256, 0, stream>>>(xb, wvb, v_b, vtmp, T_SEQ, C_EMB, C_EMB);

    transpose_bf16<<<dim3(T_SEQ / 64, C_EMB / 64), 256, 0, stream>>>(vtmp, vt);

    attn_win<<<NH * (T_SEQ / 64), 256, 0, stream>>>(qbuf, kbuf, vt, yatt);

    gemm_bt<1><<<ggrid, 256, 0, stream>>>(yatt, wob, o_b, out, T_SEQ, C_EMB, C_EMB);
}

// Round 4
// 204.077 us; speedup vs baseline: 1.2045x; 1.2045x over previous
//
#include <hip/hip_runtime.h>
#include <hip/hip_bf16.h>
#include <cstdint>

#define T_SEQ 4096
#define C_EMB 1024
#define NH    16
#define HS    64
#define WIN   256
#define SINKSZ 4

typedef short  short8  __attribute__((ext_vector_type(8)));
typedef short  short4v __attribute__((ext_vector_type(4)));
typedef float  f32x4   __attribute__((ext_vector_type(4)));
typedef unsigned short u16;

__device__ __forceinline__ u16 f2bf(float f) {
    uint32_t u = __builtin_bit_cast(uint32_t, f);
    u = u + 0x7fffu + ((u >> 16) & 1u);   // RNE
    return (u16)(u >> 16);
}

__device__ __forceinline__ void gload_lds16(const void* g, void* l) {
    __builtin_amdgcn_global_load_lds(
        (const __attribute__((address_space(1))) uint32_t*)g,
        (__attribute__((address_space(3))) uint32_t*)l, 16, 0, 0);
}

// ---------------- fused f32 -> bf16 convert (x + 4 weights, 1 launch) ----------------
__global__ __launch_bounds__(256) void cvt_all(const float* __restrict__ x,
                                               const float* __restrict__ w0,
                                               const float* __restrict__ w1,
                                               const float* __restrict__ w2,
                                               const float* __restrict__ w3,
                                               u16* __restrict__ xb,
                                               u16* __restrict__ o0,
                                               u16* __restrict__ o1,
                                               u16* __restrict__ o2,
                                               u16* __restrict__ o3) {
    const int NX = (T_SEQ * C_EMB) / 4;    // 1048576 float4
    const int NW = (C_EMB * C_EMB) / 4;    // 262144 float4
    int i = blockIdx.x * 256 + threadIdx.x;
    const float* src; u16* dst; int off;
    if (i < NX) { src = x; dst = xb; off = i; }
    else {
        int j = i - NX;
        int w = j >> 18;                    // /262144
        off = j & (NW - 1);
        src = w == 0 ? w0 : w == 1 ? w1 : w == 2 ? w2 : w3;
        dst = w == 0 ? o0 : w == 1 ? o1 : w == 2 ? o2 : o3;
    }
    float4 v = ((const float4*)src)[off];
    ushort4 o;
    o.x = f2bf(v.x); o.y = f2bf(v.y); o.z = f2bf(v.z); o.w = f2bf(v.w);
    ((ushort4*)dst)[off] = o;
}

// ---------------- 2-phase double-buffered bf16 GEMM core ----------------
// C(128x128 tile at m0,n0) = A(M,K) @ Bt(N,K)^T + bias.  BK=32.
// Per K-step: issue next-tile global_load_lds BEFORE current tile's
// ds_read+MFMA (loads fly under compute), single barrier per step
// (compiler drains vmcnt+lgkmcnt there -> next buffer valid, reads done).
template<int OUT_F32>
__device__ __forceinline__ void gemm_tile(const u16* __restrict__ A,
                                          const u16* __restrict__ Bt,
                                          const float* __restrict__ bias,
                                          void* __restrict__ Cout,
                                          int m0, int n0, int N, int K) {
    __shared__ u16 As[2][128 * 32];
    __shared__ u16 Bs[2][128 * 32];
    const int tid = threadIdx.x;
    const int l = tid & 63, wid = tid >> 6;
    const int lr = l & 15, g = l >> 4;
    const int wm = (wid >> 1) * 64, wn = (wid & 1) * 64;

    const int rowA = tid >> 2, colA = (tid & 3) << 3;  // e = tid (rows 0..63) and e+256 (rows 64..127)
    const u16* gA0 = A  + (size_t)(m0 + rowA) * K + colA;
    const u16* gA1 = A  + (size_t)(m0 + 64 + rowA) * K + colA;
    const u16* gB0 = Bt + (size_t)(n0 + rowA) * K + colA;
    const u16* gB1 = Bt + (size_t)(n0 + 64 + rowA) * K + colA;
    const int eo0 = tid * 8, eo1 = (256 + tid) * 8;

    f32x4 acc[4][4];
#pragma unroll
    for (int m = 0; m < 4; ++m)
#pragma unroll
        for (int n = 0; n < 4; ++n)
            acc[m][n] = (f32x4){0.f, 0.f, 0.f, 0.f};

    // prologue: stage tile 0
    gload_lds16(gA0, &As[0][eo0]);
    gload_lds16(gA1, &As[0][eo1]);
    gload_lds16(gB0, &Bs[0][eo0]);
    gload_lds16(gB1, &Bs[0][eo1]);
    __syncthreads();

    const int nk = K >> 5;
    for (int t = 0; t < nk; ++t) {
        const int cur = t & 1;
        if (t + 1 < nk) {                  // stage next tile (overlaps compute below)
            int ko = (t + 1) << 5;
            gload_lds16(gA0 + ko, &As[cur ^ 1][eo0]);
            gload_lds16(gA1 + ko, &As[cur ^ 1][eo1]);
            gload_lds16(gB0 + ko, &Bs[cur ^ 1][eo0]);
            gload_lds16(gB1 + ko, &Bs[cur ^ 1][eo1]);
        }
        short8 af[4], bf[4];
#pragma unroll
        for (int m = 0; m < 4; ++m)
            af[m] = *(const short8*)(&As[cur][(wm + m * 16 + lr) * 32 + g * 8]);
#pragma unroll
        for (int n = 0; n < 4; ++n)
            bf[n] = *(const short8*)(&Bs[cur][(wn + n * 16 + lr) * 32 + g * 8]);
#pragma unroll
        for (int m = 0; m < 4; ++m)
#pragma unroll
            for (int n = 0; n < 4; ++n)
                acc[m][n] = __builtin_amdgcn_mfma_f32_16x16x32_bf16(af[m], bf[n], acc[m][n], 0, 0, 0);
        __syncthreads();   // drains vmcnt (next buf ready) + ensures all reads of cur done
    }

    // epilogue: C row = m0+wm+16m+4g+r, col = n0+wn+16n+lr
#pragma unroll
    for (int n = 0; n < 4; ++n) {
        int col = n0 + wn + n * 16 + lr;
        float b = bias[col];
#pragma unroll
        for (int m = 0; m < 4; ++m) {
            int rowb = m0 + wm + m * 16 + g * 4;
#pragma unroll
            for (int r = 0; r < 4; ++r) {
                float v = acc[m][n][r] + b;
                if (OUT_F32) ((float*)Cout)[(size_t)(rowb + r) * N + col] = v;
                else         ((u16*)Cout)[(size_t)(rowb + r) * N + col] = f2bf(v);
            }
        }
    }
}

// Fused QKV projection: grid (32, 24); y -> {weight segment, 128-col tile}
__global__ __launch_bounds__(256) void gemm_qkv(const u16* __restrict__ A,
                                                const u16* __restrict__ Wq,
                                                const u16* __restrict__ Wk,
                                                const u16* __restrict__ Wv,
                                                const float* __restrict__ bq,
                                                const float* __restrict__ bk,
                                                const float* __restrict__ bv,
                                                u16* __restrict__ Oq,
                                                u16* __restrict__ Ok,
                                                u16* __restrict__ Ov) {
    const int m0 = blockIdx.x * 128;
    const int y = blockIdx.y;
    const int seg = y >> 3;                 // 0,1,2 -> q,k,v (block-uniform)
    const int n0 = (y & 7) * 128;
    const u16* Bt = seg == 0 ? Wq : seg == 1 ? Wk : Wv;
    const float* bias = seg == 0 ? bq : seg == 1 ? bk : bv;
    u16* out = seg == 0 ? Oq : seg == 1 ? Ok : Ov;
    gemm_tile<0>(A, Bt, bias, out, m0, n0, C_EMB, C_EMB);
}

// O projection: grid (32, 8), f32 out
__global__ __launch_bounds__(256) void gemm_o(const u16* __restrict__ A,
                                              const u16* __restrict__ Bt,
                                              const float* __restrict__ bias,
                                              float* __restrict__ out) {
    gemm_tile<1>(A, Bt, bias, out, blockIdx.x * 128, blockIdx.y * 128, C_EMB, C_EMB);
}

// ---------------- bf16 transpose (T,C) -> (C,T) ----------------
__global__ __launch_bounds__(256) void transpose_bf16(const u16* __restrict__ src,
                                                      u16* __restrict__ dst) {
    __shared__ u16 tile[64][72];
    int t0 = blockIdx.x * 64, c0 = blockIdx.y * 64;
    int tid = threadIdx.x;
    int rp = tid >> 3, cp = (tid & 7) * 8;
#pragma unroll
    for (int p = 0; p < 2; ++p) {
        int row = p * 32 + rp;
        short8 v = *(const short8*)(src + (size_t)(t0 + row) * C_EMB + c0 + cp);
#pragma unroll
        for (int j = 0; j < 8; ++j) tile[cp + j][row] = (u16)v[j];
    }
    __syncthreads();
#pragma unroll
    for (int p = 0; p < 2; ++p) {
        int row = p * 32 + rp;
        short8 v = *(const short8*)(&tile[row][cp]);
        *(short8*)(dst + (size_t)(c0 + row) * T_SEQ + t0 + cp) = v;
    }
}

// ---------------- windowed flash attention ----------------
// P is WAVE-PRIVATE -> no barriers needed (same-wave ds_write->ds_read is
// ordered by lgkmcnt, compiler inserts it). Stride padded 32->40 shorts:
// b128 read start bank = (20*lr + 4*g) % 32 -> 2-way max (free).
__global__ __launch_bounds__(256) void attn_win(const u16* __restrict__ Q,
                                                const u16* __restrict__ Kk,
                                                const u16* __restrict__ Vt,
                                                u16* __restrict__ Yo) {
    __shared__ u16 P[4][16][40];
    const int tid = threadIdx.x;
    const int l = tid & 63, wid = tid >> 6;
    const int lr = l & 15, g = l >> 4;
    const int h  = blockIdx.x >> 6;
    const int qs = (blockIdx.x & 63) * 64;
    const int qrow = qs + wid * 16 + lr;
    const float scale = 0.125f;

    short8 qf[2];
#pragma unroll
    for (int u = 0; u < 2; ++u)
        qf[u] = *(const short8*)(Q + (size_t)qrow * C_EMB + h * HS + u * 32 + g * 8);

    f32x4 acc[4];
#pragma unroll
    for (int dt = 0; dt < 4; ++dt) acc[dt] = (f32x4){0.f, 0.f, 0.f, 0.f};
    float mrun = -1e30f, lsum = 0.f;

    int ks = qs - (WIN - 1);
    if (ks < 0) ks = 0; else ks &= ~31;
    const int nch = ((qs + 64) - ks) >> 5;
    const bool sinkch = (ks > 0);
    const int total = nch + (sinkch ? 1 : 0);

    for (int ci = 0; ci < total; ++ci) {
        int kb = sinkch ? (ci == 0 ? 0 : ks + (ci - 1) * 32) : ks + ci * 32;

        f32x4 s[2];
#pragma unroll
        for (int u2 = 0; u2 < 2; ++u2) {
            const u16* kr = Kk + (size_t)(kb + u2 * 16 + lr) * C_EMB + h * HS;
            short8 kf0 = *(const short8*)(kr + g * 8);
            short8 kf1 = *(const short8*)(kr + 32 + g * 8);
            f32x4 z = (f32x4){0.f, 0.f, 0.f, 0.f};
            z = __builtin_amdgcn_mfma_f32_16x16x32_bf16(kf0, qf[0], z, 0, 0, 0);
            z = __builtin_amdgcn_mfma_f32_16x16x32_bf16(kf1, qf[1], z, 0, 0, 0);
            s[u2] = z;
        }
        float pmax = -1e30f;
#pragma unroll
        for (int u2 = 0; u2 < 2; ++u2)
#pragma unroll
            for (int r = 0; r < 4; ++r) {
                int key = kb + u2 * 16 + g * 4 + r;
                bool ok = (key <= qrow) && ((key + (WIN - 1) >= qrow) || (key < SINKSZ));
                float sv = ok ? s[u2][r] * scale : -1e30f;
                s[u2][r] = sv;
                pmax = fmaxf(pmax, sv);
            }
        pmax = fmaxf(pmax, __shfl_xor(pmax, 16, 64));
        pmax = fmaxf(pmax, __shfl_xor(pmax, 32, 64));
        float mnew = fmaxf(mrun, pmax);
        float fsc = __expf(mrun - mnew);
        float psum = 0.f;
#pragma unroll
        for (int u2 = 0; u2 < 2; ++u2)
#pragma unroll
            for (int r = 0; r < 4; ++r) {
                float p = __expf(s[u2][r] - mnew);
                s[u2][r] = p;
                psum += p;
            }
        psum += __shfl_xor(psum, 16, 64);
        psum += __shfl_xor(psum, 32, 64);
        lsum = lsum * fsc + psum;
        mrun = mnew;
#pragma unroll
        for (int dt = 0; dt < 4; ++dt)
#pragma unroll
            for (int r = 0; r < 4; ++r) acc[dt][r] *= fsc;

        // write P^T (q x 32 keys) to wave-private LDS as bf16 (no barrier)
#pragma unroll
        for (int u2 = 0; u2 < 2; ++u2) {
            short4v pw;
#pragma unroll
            for (int r = 0; r < 4; ++r) pw[r] = (short)f2bf(s[u2][r]);
            *(short4v*)(&P[wid][lr][u2 * 16 + g * 4]) = pw;
        }
        // PV: y^T[d][q] += V^T[d,k] . P^T[k,q]
#pragma unroll
        for (int dt = 0; dt < 4; ++dt) {
            short8 vf = *(const short8*)(Vt + (size_t)(h * HS + dt * 16 + lr) * T_SEQ + kb + g * 8);
            short8 pf = *(const short8*)(&P[wid][lr][g * 8]);
            acc[dt] = __builtin_amdgcn_mfma_f32_16x16x32_bf16(vf, pf, acc[dt], 0, 0, 0);
        }
    }

    float inv = 1.f / lsum;
#pragma unroll
    for (int dt = 0; dt < 4; ++dt) {
        short4v w;
#pragma unroll
        for (int r = 0; r < 4; ++r) w[r] = (short)f2bf(acc[dt][r] * inv);
        *(short4v*)(Yo + (size_t)qrow * C_EMB + h * HS + dt * 16 + g * 4) = w;
    }
}

extern "C" void kernel_launch(void* const* d_in, const int* in_sizes, int n_in,
                              void* d_out, int out_size, void* d_ws, size_t ws_size,
                              hipStream_t stream) {
    const float* x   = (const float*)d_in[0];
    const float* q_w = (const float*)d_in[1];
    const float* q_b = (const float*)d_in[2];
    const float* k_w = (const float*)d_in[3];
    const float* k_b = (const float*)d_in[4];
    const float* v_w = (const float*)d_in[5];
    const float* v_b = (const float*)d_in[6];
    const float* o_w = (const float*)d_in[7];
    const float* o_b = (const float*)d_in[8];
    float* out = (float*)d_out;

    char* ws = (char*)d_ws;
    const size_t SZ_TC = (size_t)T_SEQ * C_EMB * 2;
    const size_t SZ_W  = (size_t)C_EMB * C_EMB * 2;
    u16* xb   = (u16*)(ws);                 ws += SZ_TC;
    u16* wqb  = (u16*)(ws);                 ws += SZ_W;
    u16* wkb  = (u16*)(ws);                 ws += SZ_W;
    u16* wvb  = (u16*)(ws);                 ws += SZ_W;
    u16* wob  = (u16*)(ws);                 ws += SZ_W;
    u16* qbuf = (u16*)(ws);                 ws += SZ_TC;
    u16* kbuf = (u16*)(ws);                 ws += SZ_TC;
    u16* vtmp = (u16*)(ws);                 ws += SZ_TC;
    u16* vt   = (u16*)(ws);                 ws += SZ_TC;
    u16* yatt = (u16*)(ws);                 ws += SZ_TC;

    const int nCvt = (T_SEQ * C_EMB + 4 * C_EMB * C_EMB) / 4;  // float4 count
    cvt_all<<<nCvt / 256, 256, 0, stream>>>(x, q_w, k_w, v_w, o_w,
                                            xb, wqb, wkb, wvb, wob);

    gemm_qkv<<<dim3(T_SEQ / 128, 24), 256, 0, stream>>>(xb, wqb, wkb, wvb,
                                                        q_b, k_b, v_b,
                                                        qbuf, kbuf, vtmp);

    transpose_bf16<<<dim3(T_SEQ / 64, C_EMB / 64), 256, 0, stream>>>(vtmp, vt);

    attn_win<<<NH * (T_SEQ / 64), 256, 0, stream>>>(qbuf, kbuf, vt, yatt);

    gemm_o<<<dim3(T_SEQ / 128, C_EMB / 128), 256, 0, stream>>>(yatt, wob, o_b, out);
}

// Round 5
// 183.713 us; speedup vs baseline: 1.3380x; 1.1108x over previous
//
#include <hip/hip_runtime.h>
#include <hip/hip_bf16.h>
#include <cstdint>

#define T_SEQ 4096
#define C_EMB 1024
#define NH    16
#define HS    64
#define WIN   256
#define SINKSZ 4
#define QBLK  128

typedef short  short8  __attribute__((ext_vector_type(8)));
typedef short  short4v __attribute__((ext_vector_type(4)));
typedef float  f32x4   __attribute__((ext_vector_type(4)));
typedef unsigned short u16;

__device__ __forceinline__ u16 f2bf(float f) {
    uint32_t u = __builtin_bit_cast(uint32_t, f);
    u = u + 0x7fffu + ((u >> 16) & 1u);   // RNE
    return (u16)(u >> 16);
}

__device__ __forceinline__ void gload_lds16(const void* g, void* l) {
    __builtin_amdgcn_global_load_lds(
        (const __attribute__((address_space(1))) uint32_t*)g,
        (__attribute__((address_space(3))) uint32_t*)l, 16, 0, 0);
}

// ---------------- fused f32 -> bf16 convert (x + 4 weights, 1 launch) ----------------
__global__ __launch_bounds__(256) void cvt_all(const float* __restrict__ x,
                                               const float* __restrict__ w0,
                                               const float* __restrict__ w1,
                                               const float* __restrict__ w2,
                                               const float* __restrict__ w3,
                                               u16* __restrict__ xb,
                                               u16* __restrict__ o0,
                                               u16* __restrict__ o1,
                                               u16* __restrict__ o2,
                                               u16* __restrict__ o3) {
    const int NX = (T_SEQ * C_EMB) / 4;    // 1048576 float4
    const int NW = (C_EMB * C_EMB) / 4;    // 262144 float4
    int i = blockIdx.x * 256 + threadIdx.x;
    const float* src; u16* dst; int off;
    if (i < NX) { src = x; dst = xb; off = i; }
    else {
        int j = i - NX;
        int w = j >> 18;                    // /262144
        off = j & (NW - 1);
        src = w == 0 ? w0 : w == 1 ? w1 : w == 2 ? w2 : w3;
        dst = w == 0 ? o0 : w == 1 ? o1 : w == 2 ? o2 : o3;
    }
    float4 v = ((const float4*)src)[off];
    ushort4 o;
    o.x = f2bf(v.x); o.y = f2bf(v.y); o.z = f2bf(v.z); o.w = f2bf(v.w);
    ((ushort4*)dst)[off] = o;
}

// ---------------- 2-phase double-buffered bf16 GEMM core ----------------
template<int OUT_F32>
__device__ __forceinline__ void gemm_tile(const u16* __restrict__ A,
                                          const u16* __restrict__ Bt,
                                          const float* __restrict__ bias,
                                          void* __restrict__ Cout,
                                          int m0, int n0, int N, int K) {
    __shared__ u16 As[2][128 * 32];
    __shared__ u16 Bs[2][128 * 32];
    const int tid = threadIdx.x;
    const int l = tid & 63, wid = tid >> 6;
    const int lr = l & 15, g = l >> 4;
    const int wm = (wid >> 1) * 64, wn = (wid & 1) * 64;

    const int rowA = tid >> 2, colA = (tid & 3) << 3;
    const u16* gA0 = A  + (size_t)(m0 + rowA) * K + colA;
    const u16* gA1 = A  + (size_t)(m0 + 64 + rowA) * K + colA;
    const u16* gB0 = Bt + (size_t)(n0 + rowA) * K + colA;
    const u16* gB1 = Bt + (size_t)(n0 + 64 + rowA) * K + colA;
    const int eo0 = tid * 8, eo1 = (256 + tid) * 8;

    f32x4 acc[4][4];
#pragma unroll
    for (int m = 0; m < 4; ++m)
#pragma unroll
        for (int n = 0; n < 4; ++n)
            acc[m][n] = (f32x4){0.f, 0.f, 0.f, 0.f};

    gload_lds16(gA0, &As[0][eo0]);
    gload_lds16(gA1, &As[0][eo1]);
    gload_lds16(gB0, &Bs[0][eo0]);
    gload_lds16(gB1, &Bs[0][eo1]);
    __syncthreads();

    const int nk = K >> 5;
    for (int t = 0; t < nk; ++t) {
        const int cur = t & 1;
        if (t + 1 < nk) {
            int ko = (t + 1) << 5;
            gload_lds16(gA0 + ko, &As[cur ^ 1][eo0]);
            gload_lds16(gA1 + ko, &As[cur ^ 1][eo1]);
            gload_lds16(gB0 + ko, &Bs[cur ^ 1][eo0]);
            gload_lds16(gB1 + ko, &Bs[cur ^ 1][eo1]);
        }
        short8 af[4], bf[4];
#pragma unroll
        for (int m = 0; m < 4; ++m)
            af[m] = *(const short8*)(&As[cur][(wm + m * 16 + lr) * 32 + g * 8]);
#pragma unroll
        for (int n = 0; n < 4; ++n)
            bf[n] = *(const short8*)(&Bs[cur][(wn + n * 16 + lr) * 32 + g * 8]);
#pragma unroll
        for (int m = 0; m < 4; ++m)
#pragma unroll
            for (int n = 0; n < 4; ++n)
                acc[m][n] = __builtin_amdgcn_mfma_f32_16x16x32_bf16(af[m], bf[n], acc[m][n], 0, 0, 0);
        __syncthreads();
    }

#pragma unroll
    for (int n = 0; n < 4; ++n) {
        int col = n0 + wn + n * 16 + lr;
        float b = bias[col];
#pragma unroll
        for (int m = 0; m < 4; ++m) {
            int rowb = m0 + wm + m * 16 + g * 4;
#pragma unroll
            for (int r = 0; r < 4; ++r) {
                float v = acc[m][n][r] + b;
                if (OUT_F32) ((float*)Cout)[(size_t)(rowb + r) * N + col] = v;
                else         ((u16*)Cout)[(size_t)(rowb + r) * N + col] = f2bf(v);
            }
        }
    }
}

// Fused QKV projection: grid (32, 24)
__global__ __launch_bounds__(256) void gemm_qkv(const u16* __restrict__ A,
                                                const u16* __restrict__ Wq,
                                                const u16* __restrict__ Wk,
                                                const u16* __restrict__ Wv,
                                                const float* __restrict__ bq,
                                                const float* __restrict__ bk,
                                                const float* __restrict__ bv,
                                                u16* __restrict__ Oq,
                                                u16* __restrict__ Ok,
                                                u16* __restrict__ Ov) {
    const int m0 = blockIdx.x * 128;
    const int y = blockIdx.y;
    const int seg = y >> 3;
    const int n0 = (y & 7) * 128;
    const u16* Bt = seg == 0 ? Wq : seg == 1 ? Wk : Wv;
    const float* bias = seg == 0 ? bq : seg == 1 ? bk : bv;
    u16* out = seg == 0 ? Oq : seg == 1 ? Ok : Ov;
    gemm_tile<0>(A, Bt, bias, out, m0, n0, C_EMB, C_EMB);
}

// O projection: grid (32, 8), f32 out
__global__ __launch_bounds__(256) void gemm_o(const u16* __restrict__ A,
                                              const u16* __restrict__ Bt,
                                              const float* __restrict__ bias,
                                              float* __restrict__ out) {
    gemm_tile<1>(A, Bt, bias, out, blockIdx.x * 128, blockIdx.y * 128, C_EMB, C_EMB);
}

// ---------------- bf16 transpose (T,C) -> (C,T) ----------------
__global__ __launch_bounds__(256) void transpose_bf16(const u16* __restrict__ src,
                                                      u16* __restrict__ dst) {
    __shared__ u16 tile[64][72];
    int t0 = blockIdx.x * 64, c0 = blockIdx.y * 64;
    int tid = threadIdx.x;
    int rp = tid >> 3, cp = (tid & 7) * 8;
#pragma unroll
    for (int p = 0; p < 2; ++p) {
        int row = p * 32 + rp;
        short8 v = *(const short8*)(src + (size_t)(t0 + row) * C_EMB + c0 + cp);
#pragma unroll
        for (int j = 0; j < 8; ++j) tile[cp + j][row] = (u16)v[j];
    }
    __syncthreads();
#pragma unroll
    for (int p = 0; p < 2; ++p) {
        int row = p * 32 + rp;
        short8 v = *(const short8*)(&tile[row][cp]);
        *(short8*)(dst + (size_t)(c0 + row) * T_SEQ + t0 + cp) = v;
    }
}

// ---------------- windowed flash attention, staged pipeline ----------------
// 8 waves x 16 q-rows = 128 q-rows/block. Per 32-key chunk: K(32x64) and
// Vt(64x32) staged to LDS by half the block each (coalesced b128/thread),
// double-buffered: issue next chunk's global->reg loads BEFORE computing
// current chunk from LDS; ds_write after compute; ONE barrier per chunk.
__global__ __launch_bounds__(512) void attn_win(const u16* __restrict__ Q,
                                                const u16* __restrict__ Kk,
                                                const u16* __restrict__ Vt,
                                                u16* __restrict__ Yo) {
    __shared__ u16 Ks[2][32][72];   // keys x dims, stride 72 (144B: b128-aligned, ~2-way banks)
    __shared__ u16 Vs[2][64][40];   // dims x keys, stride 40 (80B)
    __shared__ u16 P[8][16][40];    // per-wave P^T

    const int tid = threadIdx.x;
    const int l = tid & 63, wid = tid >> 6;
    const int lr = l & 15, g = l >> 4;
    // XCD swizzle: consecutive logical q-blocks of one head land on one XCD
    const int bx = blockIdx.x;
    const int L = (bx & 7) * 64 + (bx >> 3);   // 512 % 8 == 0 -> bijective
    const int h  = L >> 5;
    const int qs = (L & 31) * QBLK;
    const int qrow = qs + wid * 16 + lr;
    const float scale = 0.125f;

    // staging role (wave-uniform): waves 0-3 load K, waves 4-7 load V
    const int krow = tid >> 3, kco = (tid & 7) * 8;          // tid<256
    const int t2 = tid - 256;
    const int vrow = t2 >> 2, vco = (t2 & 3) * 8;            // tid>=256

    short8 qf[2];
#pragma unroll
    for (int u = 0; u < 2; ++u)
        qf[u] = *(const short8*)(Q + (size_t)qrow * C_EMB + h * HS + u * 32 + g * 8);

    f32x4 acc[4];
#pragma unroll
    for (int dt = 0; dt < 4; ++dt) acc[dt] = (f32x4){0.f, 0.f, 0.f, 0.f};
    float mrun = -1e30f, lsum = 0.f;

    int ks = qs - (WIN - 1);
    if (ks < 0) ks = 0; else ks &= ~31;
    const int nch = ((qs + QBLK) - ks) >> 5;
    const bool sinkch = (ks > 0);
    const int total = nch + (sinkch ? 1 : 0);

    // prologue: stage chunk 0
    {
        int kb0 = sinkch ? 0 : ks;
        short8 r;
        if (tid < 256) r = *(const short8*)(Kk + (size_t)(kb0 + krow) * C_EMB + h * HS + kco);
        else           r = *(const short8*)(Vt + (size_t)(h * HS + vrow) * T_SEQ + kb0 + vco);
        if (tid < 256) *(short8*)(&Ks[0][krow][kco]) = r;
        else           *(short8*)(&Vs[0][vrow][vco]) = r;
    }
    __syncthreads();

    for (int ci = 0; ci < total; ++ci) {
        const int cur = ci & 1;
        const int kb = sinkch ? (ci == 0 ? 0 : ks + (ci - 1) * 32) : ks + ci * 32;
        const bool havenext = (ci + 1 < total);
        short8 nx;
        if (havenext) {
            int kbn = sinkch ? ks + ci * 32 : ks + (ci + 1) * 32;
            if (tid < 256) nx = *(const short8*)(Kk + (size_t)(kbn + krow) * C_EMB + h * HS + kco);
            else           nx = *(const short8*)(Vt + (size_t)(h * HS + vrow) * T_SEQ + kbn + vco);
        }

        // ---- compute chunk ci from LDS buf[cur] ----
        f32x4 s[2];
#pragma unroll
        for (int u2 = 0; u2 < 2; ++u2) {
            short8 kf0 = *(const short8*)(&Ks[cur][u2 * 16 + lr][g * 8]);
            short8 kf1 = *(const short8*)(&Ks[cur][u2 * 16 + lr][32 + g * 8]);
            f32x4 z = (f32x4){0.f, 0.f, 0.f, 0.f};
            z = __builtin_amdgcn_mfma_f32_16x16x32_bf16(kf0, qf[0], z, 0, 0, 0);
            z = __builtin_amdgcn_mfma_f32_16x16x32_bf16(kf1, qf[1], z, 0, 0, 0);
            s[u2] = z;
        }
        float pmax = -1e30f;
#pragma unroll
        for (int u2 = 0; u2 < 2; ++u2)
#pragma unroll
            for (int r = 0; r < 4; ++r) {
                int key = kb + u2 * 16 + g * 4 + r;
                bool ok = (key <= qrow) && ((key + (WIN - 1) >= qrow) || (key < SINKSZ));
                float sv = ok ? s[u2][r] * scale : -1e30f;
                s[u2][r] = sv;
                pmax = fmaxf(pmax, sv);
            }
        pmax = fmaxf(pmax, __shfl_xor(pmax, 16, 64));
        pmax = fmaxf(pmax, __shfl_xor(pmax, 32, 64));
        float mnew = fmaxf(mrun, pmax);
        float fsc = __expf(mrun - mnew);
        float psum = 0.f;
#pragma unroll
        for (int u2 = 0; u2 < 2; ++u2)
#pragma unroll
            for (int r = 0; r < 4; ++r) {
                float p = __expf(s[u2][r] - mnew);
                s[u2][r] = p;
                psum += p;
            }
        psum += __shfl_xor(psum, 16, 64);
        psum += __shfl_xor(psum, 32, 64);
        lsum = lsum * fsc + psum;
        mrun = mnew;
#pragma unroll
        for (int dt = 0; dt < 4; ++dt)
#pragma unroll
            for (int r = 0; r < 4; ++r) acc[dt][r] *= fsc;

#pragma unroll
        for (int u2 = 0; u2 < 2; ++u2) {
            short4v pw;
#pragma unroll
            for (int r = 0; r < 4; ++r) pw[r] = (short)f2bf(s[u2][r]);
            *(short4v*)(&P[wid][lr][u2 * 16 + g * 4]) = pw;
        }
#pragma unroll
        for (int dt = 0; dt < 4; ++dt) {
            short8 vf = *(const short8*)(&Vs[cur][dt * 16 + lr][g * 8]);
            short8 pf = *(const short8*)(&P[wid][lr][g * 8]);
            acc[dt] = __builtin_amdgcn_mfma_f32_16x16x32_bf16(vf, pf, acc[dt], 0, 0, 0);
        }

        // ---- publish next chunk ----
        if (havenext) {
            if (tid < 256) *(short8*)(&Ks[cur ^ 1][krow][kco]) = nx;
            else           *(short8*)(&Vs[cur ^ 1][vrow][vco]) = nx;
        }
        __syncthreads();
    }

    float inv = 1.f / lsum;
#pragma unroll
    for (int dt = 0; dt < 4; ++dt) {
        short4v w;
#pragma unroll
        for (int r = 0; r < 4; ++r) w[r] = (short)f2bf(acc[dt][r] * inv);
        *(short4v*)(Yo + (size_t)qrow * C_EMB + h * HS + dt * 16 + g * 4) = w;
    }
}

extern "C" void kernel_launch(void* const* d_in, const int* in_sizes, int n_in,
                              void* d_out, int out_size, void* d_ws, size_t ws_size,
                              hipStream_t stream) {
    const float* x   = (const float*)d_in[0];
    const float* q_w = (const float*)d_in[1];
    const float* q_b = (const float*)d_in[2];
    const float* k_w = (const float*)d_in[3];
    const float* k_b = (const float*)d_in[4];
    const float* v_w = (const float*)d_in[5];
    const float* v_b = (const float*)d_in[6];
    const float* o_w = (const float*)d_in[7];
    const float* o_b = (const float*)d_in[8];
    float* out = (float*)d_out;

    char* ws = (char*)d_ws;
    const size_t SZ_TC = (size_t)T_SEQ * C_EMB * 2;
    const size_t SZ_W  = (size_t)C_EMB * C_EMB * 2;
    u16* xb   = (u16*)(ws);                 ws += SZ_TC;
    u16* wqb  = (u16*)(ws);                 ws += SZ_W;
    u16* wkb  = (u16*)(ws);                 ws += SZ_W;
    u16* wvb  = (u16*)(ws);                 ws += SZ_W;
    u16* wob  = (u16*)(ws);                 ws += SZ_W;
    u16* qbuf = (u16*)(ws);                 ws += SZ_TC;
    u16* kbuf = (u16*)(ws);                 ws += SZ_TC;
    u16* vtmp = (u16*)(ws);                 ws += SZ_TC;
    u16* vt   = (u16*)(ws);                 ws += SZ_TC;
    u16* yatt = (u16*)(ws);                 ws += SZ_TC;

    const int nCvt = (T_SEQ * C_EMB + 4 * C_EMB * C_EMB) / 4;
    cvt_all<<<nCvt / 256, 256, 0, stream>>>(x, q_w, k_w, v_w, o_w,
                                            xb, wqb, wkb, wvb, wob);

    gemm_qkv<<<dim3(T_SEQ / 128, 24), 256, 0, stream>>>(xb, wqb, wkb, wvb,
                                                        q_b, k_b, v_b,
                                                        qbuf, kbuf, vtmp);

    transpose_bf16<<<dim3(T_SEQ / 64, C_EMB / 64), 256, 0, stream>>>(vtmp, vt);

    attn_win<<<NH * (T_SEQ / QBLK), 512, 0, stream>>>(qbuf, kbuf, vt, yatt);

    gemm_o<<<dim3(T_SEQ / 128, C_EMB / 128), 256, 0, stream>>>(yatt, wob, o_b, out);
}

// Round 7
// 180.339 us; speedup vs baseline: 1.3630x; 1.0187x over previous
//
#include <hip/hip_runtime.h>
#include <hip/hip_bf16.h>
#include <cstdint>

#define T_SEQ 4096
#define C_EMB 1024
#define NH    16
#define HS    64
#define WIN   256
#define SINKSZ 4
#define QBLK  128

typedef short  short8  __attribute__((ext_vector_type(8)));
typedef short  short4v __attribute__((ext_vector_type(4)));
typedef float  f32x4   __attribute__((ext_vector_type(4)));
typedef unsigned short u16;

__device__ __forceinline__ u16 f2bf(float f) {
    uint32_t u = __builtin_bit_cast(uint32_t, f);
    u = u + 0x7fffu + ((u >> 16) & 1u);   // RNE
    return (u16)(u >> 16);
}

__device__ __forceinline__ void gload_lds16(const void* g, void* l) {
    __builtin_amdgcn_global_load_lds(
        (const __attribute__((address_space(1))) uint32_t*)g,
        (__attribute__((address_space(3))) uint32_t*)l, 16, 0, 0);
}

// ---------------- fused f32 -> bf16 convert (x + 4 weights, 1 launch) ----------------
__global__ __launch_bounds__(256) void cvt_all(const float* __restrict__ x,
                                               const float* __restrict__ w0,
                                               const float* __restrict__ w1,
                                               const float* __restrict__ w2,
                                               const float* __restrict__ w3,
                                               u16* __restrict__ xb,
                                               u16* __restrict__ o0,
                                               u16* __restrict__ o1,
                                               u16* __restrict__ o2,
                                               u16* __restrict__ o3) {
    const int NX = (T_SEQ * C_EMB) / 4;    // 1048576 float4
    const int NW = (C_EMB * C_EMB) / 4;    // 262144 float4
    int i = blockIdx.x * 256 + threadIdx.x;
    const float* src; u16* dst; int off;
    if (i < NX) { src = x; dst = xb; off = i; }
    else {
        int j = i - NX;
        int w = j >> 18;                    // /262144
        off = j & (NW - 1);
        src = w == 0 ? w0 : w == 1 ? w1 : w == 2 ? w2 : w3;
        dst = w == 0 ? o0 : w == 1 ? o1 : w == 2 ? o2 : o3;
    }
    float4 v = ((const float4*)src)[off];
    ushort4 o;
    o.x = f2bf(v.x); o.y = f2bf(v.y); o.z = f2bf(v.z); o.w = f2bf(v.w);
    ((ushort4*)dst)[off] = o;
}

// ---------------- 2-phase double-buffered bf16 GEMM core ----------------
template<int OUT_F32>
__device__ __forceinline__ void gemm_tile(const u16* __restrict__ A,
                                          const u16* __restrict__ Bt,
                                          const float* __restrict__ bias,
                                          void* __restrict__ Cout,
                                          int m0, int n0, int N, int K) {
    __shared__ u16 As[2][128 * 32];
    __shared__ u16 Bs[2][128 * 32];
    const int tid = threadIdx.x;
    const int l = tid & 63, wid = tid >> 6;
    const int lr = l & 15, g = l >> 4;
    const int wm = (wid >> 1) * 64, wn = (wid & 1) * 64;

    const int rowA = tid >> 2, colA = (tid & 3) << 3;
    const u16* gA0 = A  + (size_t)(m0 + rowA) * K + colA;
    const u16* gA1 = A  + (size_t)(m0 + 64 + rowA) * K + colA;
    const u16* gB0 = Bt + (size_t)(n0 + rowA) * K + colA;
    const u16* gB1 = Bt + (size_t)(n0 + 64 + rowA) * K + colA;
    const int eo0 = tid * 8, eo1 = (256 + tid) * 8;

    f32x4 acc[4][4];
#pragma unroll
    for (int m = 0; m < 4; ++m)
#pragma unroll
        for (int n = 0; n < 4; ++n)
            acc[m][n] = (f32x4){0.f, 0.f, 0.f, 0.f};

    gload_lds16(gA0, &As[0][eo0]);
    gload_lds16(gA1, &As[0][eo1]);
    gload_lds16(gB0, &Bs[0][eo0]);
    gload_lds16(gB1, &Bs[0][eo1]);
    __syncthreads();

    const int nk = K >> 5;
    for (int t = 0; t < nk; ++t) {
        const int cur = t & 1;
        if (t + 1 < nk) {
            int ko = (t + 1) << 5;
            gload_lds16(gA0 + ko, &As[cur ^ 1][eo0]);
            gload_lds16(gA1 + ko, &As[cur ^ 1][eo1]);
            gload_lds16(gB0 + ko, &Bs[cur ^ 1][eo0]);
            gload_lds16(gB1 + ko, &Bs[cur ^ 1][eo1]);
        }
        short8 af[4], bf[4];
#pragma unroll
        for (int m = 0; m < 4; ++m)
            af[m] = *(const short8*)(&As[cur][(wm + m * 16 + lr) * 32 + g * 8]);
#pragma unroll
        for (int n = 0; n < 4; ++n)
            bf[n] = *(const short8*)(&Bs[cur][(wn + n * 16 + lr) * 32 + g * 8]);
#pragma unroll
        for (int m = 0; m < 4; ++m)
#pragma unroll
            for (int n = 0; n < 4; ++n)
                acc[m][n] = __builtin_amdgcn_mfma_f32_16x16x32_bf16(af[m], bf[n], acc[m][n], 0, 0, 0);
        __syncthreads();
    }

#pragma unroll
    for (int n = 0; n < 4; ++n) {
        int col = n0 + wn + n * 16 + lr;
        float b = bias[col];
#pragma unroll
        for (int m = 0; m < 4; ++m) {
            int rowb = m0 + wm + m * 16 + g * 4;
#pragma unroll
            for (int r = 0; r < 4; ++r) {
                float v = acc[m][n][r] + b;
                if (OUT_F32) ((float*)Cout)[(size_t)(rowb + r) * N + col] = v;
                else         ((u16*)Cout)[(size_t)(rowb + r) * N + col] = f2bf(v);
            }
        }
    }
}

// Fused QKV projection: grid (32, 24)
__global__ __launch_bounds__(256) void gemm_qkv(const u16* __restrict__ A,
                                                const u16* __restrict__ Wq,
                                                const u16* __restrict__ Wk,
                                                const u16* __restrict__ Wv,
                                                const float* __restrict__ bq,
                                                const float* __restrict__ bk,
                                                const float* __restrict__ bv,
                                                u16* __restrict__ Oq,
                                                u16* __restrict__ Ok,
                                                u16* __restrict__ Ov) {
    const int m0 = blockIdx.x * 128;
    const int y = blockIdx.y;
    const int seg = y >> 3;
    const int n0 = (y & 7) * 128;
    const u16* Bt = seg == 0 ? Wq : seg == 1 ? Wk : Wv;
    const float* bias = seg == 0 ? bq : seg == 1 ? bk : bv;
    u16* out = seg == 0 ? Oq : seg == 1 ? Ok : Ov;
    gemm_tile<0>(A, Bt, bias, out, m0, n0, C_EMB, C_EMB);
}

// O projection: grid (32, 8), f32 out
__global__ __launch_bounds__(256) void gemm_o(const u16* __restrict__ A,
                                              const u16* __restrict__ Bt,
                                              const float* __restrict__ bias,
                                              float* __restrict__ out) {
    gemm_tile<1>(A, Bt, bias, out, blockIdx.x * 128, blockIdx.y * 128, C_EMB, C_EMB);
}

// ---------------- windowed flash attention, staged pipeline ----------------
// 8 waves x 16 q-rows = 128 q-rows/block. Per 32-key chunk: K(32x64) staged
// row-major; V(32 keys x 64 dims, row-major in global) staged TRANSPOSED into
// Vs via scalar ds_writes (fuses the old transpose kernel: coalesced global
// read, ~2-way LDS write conflicts, kills an 8MB HBM round-trip + a launch).
// Double-buffered: next chunk's global->reg loads issued BEFORE computing
// current chunk from LDS; publish after compute; ONE barrier per chunk.
__global__ __launch_bounds__(512) void attn_win(const u16* __restrict__ Q,
                                                const u16* __restrict__ Kk,
                                                const u16* __restrict__ V,
                                                u16* __restrict__ Yo) {
    __shared__ u16 Ks[2][32][72];   // keys x dims, stride 72 (2-way banks on read)
    __shared__ u16 Vs[2][64][40];   // dims x keys, stride 40 (2-way banks on read)
    __shared__ u16 P[8][16][40];    // per-wave P^T

    const int tid = threadIdx.x;
    const int l = tid & 63, wid = tid >> 6;
    const int lr = l & 15, g = l >> 4;
    // XCD swizzle: consecutive logical q-blocks of one head land on one XCD
    const int bx = blockIdx.x;
    const int L = (bx & 7) * 64 + (bx >> 3);   // 512 % 8 == 0 -> bijective
    const int h  = L >> 5;
    const int qs = (L & 31) * QBLK;
    const int qrow = qs + wid * 16 + lr;
    const float scale = 0.125f;

    // staging roles (wave-uniform): waves 0-3 load K, waves 4-7 load+transpose V
    const int krow = tid >> 3, kco = (tid & 7) * 8;          // tid<256
    const int t2 = tid - 256;
    const int vkr = t2 >> 3, vdc = (t2 & 7) * 8;             // tid>=256: key row, dim col

    short8 qf[2];
#pragma unroll
    for (int u = 0; u < 2; ++u)
        qf[u] = *(const short8*)(Q + (size_t)qrow * C_EMB + h * HS + u * 32 + g * 8);

    f32x4 acc[4];
#pragma unroll
    for (int dt = 0; dt < 4; ++dt) acc[dt] = (f32x4){0.f, 0.f, 0.f, 0.f};
    float mrun = -1e30f, lsum = 0.f;

    int ks = qs - (WIN - 1);
    if (ks < 0) ks = 0; else ks &= ~31;
    const int nch = ((qs + QBLK) - ks) >> 5;
    const bool sinkch = (ks > 0);
    const int total = nch + (sinkch ? 1 : 0);

    // prologue: stage chunk 0
    {
        int kb0 = sinkch ? 0 : ks;
        if (tid < 256) {
            short8 r = *(const short8*)(Kk + (size_t)(kb0 + krow) * C_EMB + h * HS + kco);
            *(short8*)(&Ks[0][krow][kco]) = r;
        } else {
            short8 r = *(const short8*)(V + (size_t)(kb0 + vkr) * C_EMB + h * HS + vdc);
#pragma unroll
            for (int j = 0; j < 8; ++j) Vs[0][vdc + j][vkr] = (u16)r[j];
        }
    }
    __syncthreads();

    for (int ci = 0; ci < total; ++ci) {
        const int cur = ci & 1;
        const int kb = sinkch ? (ci == 0 ? 0 : ks + (ci - 1) * 32) : ks + ci * 32;
        const bool havenext = (ci + 1 < total);
        short8 nx;
        if (havenext) {
            int kbn = sinkch ? ks + ci * 32 : ks + (ci + 1) * 32;
            if (tid < 256) nx = *(const short8*)(Kk + (size_t)(kbn + krow) * C_EMB + h * HS + kco);
            else           nx = *(const short8*)(V  + (size_t)(kbn + vkr) * C_EMB + h * HS + vdc);
        }

        // ---- compute chunk ci from LDS buf[cur] ----
        f32x4 s[2];
        __builtin_amdgcn_s_setprio(1);
#pragma unroll
        for (int u2 = 0; u2 < 2; ++u2) {
            short8 kf0 = *(const short8*)(&Ks[cur][u2 * 16 + lr][g * 8]);
            short8 kf1 = *(const short8*)(&Ks[cur][u2 * 16 + lr][32 + g * 8]);
            f32x4 z = (f32x4){0.f, 0.f, 0.f, 0.f};
            z = __builtin_amdgcn_mfma_f32_16x16x32_bf16(kf0, qf[0], z, 0, 0, 0);
            z = __builtin_amdgcn_mfma_f32_16x16x32_bf16(kf1, qf[1], z, 0, 0, 0);
            s[u2] = z;
        }
        __builtin_amdgcn_s_setprio(0);
        float pmax = -1e30f;
#pragma unroll
        for (int u2 = 0; u2 < 2; ++u2)
#pragma unroll
            for (int r = 0; r < 4; ++r) {
                int key = kb + u2 * 16 + g * 4 + r;
                bool ok = (key <= qrow) && ((key + (WIN - 1) >= qrow) || (key < SINKSZ));
                float sv = ok ? s[u2][r] * scale : -1e30f;
                s[u2][r] = sv;
                pmax = fmaxf(pmax, sv);
            }
        pmax = fmaxf(pmax, __shfl_xor(pmax, 16, 64));
        pmax = fmaxf(pmax, __shfl_xor(pmax, 32, 64));
        float mnew = fmaxf(mrun, pmax);
        float fsc = __expf(mrun - mnew);
        float psum = 0.f;
#pragma unroll
        for (int u2 = 0; u2 < 2; ++u2)
#pragma unroll
            for (int r = 0; r < 4; ++r) {
                float p = __expf(s[u2][r] - mnew);
                s[u2][r] = p;
                psum += p;
            }
        psum += __shfl_xor(psum, 16, 64);
        psum += __shfl_xor(psum, 32, 64);
        lsum = lsum * fsc + psum;
        mrun = mnew;
#pragma unroll
        for (int dt = 0; dt < 4; ++dt)
#pragma unroll
            for (int r = 0; r < 4; ++r) acc[dt][r] *= fsc;

#pragma unroll
        for (int u2 = 0; u2 < 2; ++u2) {
            short4v pw;
#pragma unroll
            for (int r = 0; r < 4; ++r) pw[r] = (short)f2bf(s[u2][r]);
            *(short4v*)(&P[wid][lr][u2 * 16 + g * 4]) = pw;
        }
        __builtin_amdgcn_s_setprio(1);
#pragma unroll
        for (int dt = 0; dt < 4; ++dt) {
            short8 vf = *(const short8*)(&Vs[cur][dt * 16 + lr][g * 8]);
            short8 pf = *(const short8*)(&P[wid][lr][g * 8]);
            acc[dt] = __builtin_amdgcn_mfma_f32_16x16x32_bf16(vf, pf, acc[dt], 0, 0, 0);
        }
        __builtin_amdgcn_s_setprio(0);

        // ---- publish next chunk ----
        if (havenext) {
            if (tid < 256) {
                *(short8*)(&Ks[cur ^ 1][krow][kco]) = nx;
            } else {
#pragma unroll
                for (int j = 0; j < 8; ++j) Vs[cur ^ 1][vdc + j][vkr] = (u16)nx[j];
            }
        }
        __syncthreads();
    }

    float inv = 1.f / lsum;
#pragma unroll
    for (int dt = 0; dt < 4; ++dt) {
        short4v w;
#pragma unroll
        for (int r = 0; r < 4; ++r) w[r] = (short)f2bf(acc[dt][r] * inv);
        *(short4v*)(Yo + (size_t)qrow * C_EMB + h * HS + dt * 16 + g * 4) = w;
    }
}

extern "C" void kernel_launch(void* const* d_in, const int* in_sizes, int n_in,
                              void* d_out, int out_size, void* d_ws, size_t ws_size,
                              hipStream_t stream) {
    const float* x   = (const float*)d_in[0];
    const float* q_w = (const float*)d_in[1];
    const float* q_b = (const float*)d_in[2];
    const float* k_w = (const float*)d_in[3];
    const float* k_b = (const float*)d_in[4];
    const float* v_w = (const float*)d_in[5];
    const float* v_b = (const float*)d_in[6];
    const float* o_w = (const float*)d_in[7];
    const float* o_b = (const float*)d_in[8];
    float* out = (float*)d_out;

    char* ws = (char*)d_ws;
    const size_t SZ_TC = (size_t)T_SEQ * C_EMB * 2;
    const size_t SZ_W  = (size_t)C_EMB * C_EMB * 2;
    u16* xb   = (u16*)(ws);                 ws += SZ_TC;
    u16* wqb  = (u16*)(ws);                 ws += SZ_W;
    u16* wkb  = (u16*)(ws);                 ws += SZ_W;
    u16* wvb  = (u16*)(ws);                 ws += SZ_W;
    u16* wob  = (u16*)(ws);                 ws += SZ_W;
    u16* qbuf = (u16*)(ws);                 ws += SZ_TC;
    u16* kbuf = (u16*)(ws);                 ws += SZ_TC;
    u16* vbuf = (u16*)(ws);                 ws += SZ_TC;
    u16* yatt = (u16*)(ws);                 ws += SZ_TC;

    const int nCvt = (T_SEQ * C_EMB + 4 * C_EMB * C_EMB) / 4;
    cvt_all<<<nCvt / 256, 256, 0, stream>>>(x, q_w, k_w, v_w, o_w,
                                            xb, wqb, wkb, wvb, wob);

    gemm_qkv<<<dim3(T_SEQ / 128, 24), 256, 0, stream>>>(xb, wqb, wkb, wvb,
                                                        q_b, k_b, v_b,
                                                        qbuf, kbuf, vbuf);

    attn_win<<<NH * (T_SEQ / QBLK), 512, 0, stream>>>(qbuf, kbuf, vbuf, yatt);

    gemm_o<<<dim3(T_SEQ / 128, C_EMB / 128), 256, 0, stream>>>(yatt, wob, o_b, out);
}

// Round 9
// 177.260 us; speedup vs baseline: 1.3867x; 1.0174x over previous
//
#include <hip/hip_runtime.h>
#include <hip/hip_bf16.h>
#include <cstdint>

#define T_SEQ 4096
#define C_EMB 1024
#define NH    16
#define HS    64
#define WIN   256
#define SINKSZ 4
#define QBLK  128

typedef short  short8  __attribute__((ext_vector_type(8)));
typedef short  short4v __attribute__((ext_vector_type(4)));
typedef float  f32x4   __attribute__((ext_vector_type(4)));
typedef unsigned short u16;

__device__ __forceinline__ u16 f2bf(float f) {
    uint32_t u = __builtin_bit_cast(uint32_t, f);
    u = u + 0x7fffu + ((u >> 16) & 1u);   // RNE
    return (u16)(u >> 16);
}

__device__ __forceinline__ void gload_lds16(const void* g, void* l) {
    __builtin_amdgcn_global_load_lds(
        (const __attribute__((address_space(1))) uint32_t*)g,
        (__attribute__((address_space(3))) uint32_t*)l, 16, 0, 0);
}

// ---------------- fused f32 -> bf16 convert (x + 4 weights, 1 launch) ----------------
__global__ __launch_bounds__(256) void cvt_all(const float* __restrict__ x,
                                               const float* __restrict__ w0,
                                               const float* __restrict__ w1,
                                               const float* __restrict__ w2,
                                               const float* __restrict__ w3,
                                               u16* __restrict__ xb,
                                               u16* __restrict__ o0,
                                               u16* __restrict__ o1,
                                               u16* __restrict__ o2,
                                               u16* __restrict__ o3) {
    const int NX = (T_SEQ * C_EMB) / 4;    // 1048576 float4
    const int NW = (C_EMB * C_EMB) / 4;    // 262144 float4
    int i = blockIdx.x * 256 + threadIdx.x;
    const float* src; u16* dst; int off;
    if (i < NX) { src = x; dst = xb; off = i; }
    else {
        int j = i - NX;
        int w = j >> 18;                    // /262144
        off = j & (NW - 1);
        src = w == 0 ? w0 : w == 1 ? w1 : w == 2 ? w2 : w3;
        dst = w == 0 ? o0 : w == 1 ? o1 : w == 2 ? o2 : o3;
    }
    float4 v = ((const float4*)src)[off];
    ushort4 o;
    o.x = f2bf(v.x); o.y = f2bf(v.y); o.z = f2bf(v.z); o.w = f2bf(v.w);
    ((ushort4*)dst)[off] = o;
}

// ---------------- 2-phase double-buffered bf16 GEMM core ----------------
// BM x 128 output tile, BK=32.  BM=128: 4 waves as 2x2 of 64x64 (acc 4x4).
// BM=64: 4 waves as 2x2 of 32x64 (acc 2x4) -> 2x the blocks for small-N GEMMs
// (gemm_o at BM=128 was 256 blocks = 1 block/CU -> zero inter-block overlap).
template<int OUT_F32, int BM>
__device__ __forceinline__ void gemm_tile(const u16* __restrict__ A,
                                          const u16* __restrict__ Bt,
                                          const float* __restrict__ bias,
                                          void* __restrict__ Cout,
                                          int m0, int n0, int N, int K) {
    constexpr int MR = BM / 32;            // m-fragments per wave
    __shared__ u16 As[2][BM * 32];
    __shared__ u16 Bs[2][128 * 32];
    const int tid = threadIdx.x;
    const int l = tid & 63, wid = tid >> 6;
    const int lr = l & 15, g = l >> 4;
    const int wm = (wid >> 1) * (BM / 2), wn = (wid & 1) * 64;

    const int rowA = tid >> 2, colA = (tid & 3) << 3;
    const u16* gA0 = A  + (size_t)(m0 + rowA) * K + colA;
    const u16* gA1 = A  + (size_t)(m0 + (BM == 128 ? 64 : 0) + rowA) * K + colA;
    const u16* gB0 = Bt + (size_t)(n0 + rowA) * K + colA;
    const u16* gB1 = Bt + (size_t)(n0 + 64 + rowA) * K + colA;
    const int eo0 = tid * 8, eo1 = (256 + tid) * 8;

    f32x4 acc[MR][4];
#pragma unroll
    for (int m = 0; m < MR; ++m)
#pragma unroll
        for (int n = 0; n < 4; ++n)
            acc[m][n] = (f32x4){0.f, 0.f, 0.f, 0.f};

    gload_lds16(gA0, &As[0][eo0]);
    if constexpr (BM == 128) gload_lds16(gA1, &As[0][eo1]);
    gload_lds16(gB0, &Bs[0][eo0]);
    gload_lds16(gB1, &Bs[0][eo1]);
    __syncthreads();

    const int nk = K >> 5;
    for (int t = 0; t < nk; ++t) {
        const int cur = t & 1;
        if (t + 1 < nk) {
            int ko = (t + 1) << 5;
            gload_lds16(gA0 + ko, &As[cur ^ 1][eo0]);
            if constexpr (BM == 128) gload_lds16(gA1 + ko, &As[cur ^ 1][eo1]);
            gload_lds16(gB0 + ko, &Bs[cur ^ 1][eo0]);
            gload_lds16(gB1 + ko, &Bs[cur ^ 1][eo1]);
        }
        short8 af[MR], bf[4];
#pragma unroll
        for (int m = 0; m < MR; ++m)
            af[m] = *(const short8*)(&As[cur][(wm + m * 16 + lr) * 32 + g * 8]);
#pragma unroll
        for (int n = 0; n < 4; ++n)
            bf[n] = *(const short8*)(&Bs[cur][(wn + n * 16 + lr) * 32 + g * 8]);
#pragma unroll
        for (int m = 0; m < MR; ++m)
#pragma unroll
            for (int n = 0; n < 4; ++n)
                acc[m][n] = __builtin_amdgcn_mfma_f32_16x16x32_bf16(af[m], bf[n], acc[m][n], 0, 0, 0);
        __syncthreads();
    }

#pragma unroll
    for (int n = 0; n < 4; ++n) {
        int col = n0 + wn + n * 16 + lr;
        float b = bias[col];
#pragma unroll
        for (int m = 0; m < MR; ++m) {
            int rowb = m0 + wm + m * 16 + g * 4;
#pragma unroll
            for (int r = 0; r < 4; ++r) {
                float v = acc[m][n][r] + b;
                if (OUT_F32) ((float*)Cout)[(size_t)(rowb + r) * N + col] = v;
                else         ((u16*)Cout)[(size_t)(rowb + r) * N + col] = f2bf(v);
            }
        }
    }
}

// Fused QKV projection: grid (32, 24)
__global__ __launch_bounds__(256) void gemm_qkv(const u16* __restrict__ A,
                                                const u16* __restrict__ Wq,
                                                const u16* __restrict__ Wk,
                                                const u16* __restrict__ Wv,
                                                const float* __restrict__ bq,
                                                const float* __restrict__ bk,
                                                const float* __restrict__ bv,
                                                u16* __restrict__ Oq,
                                                u16* __restrict__ Ok,
                                                u16* __restrict__ Ov) {
    const int m0 = blockIdx.x * 128;
    const int y = blockIdx.y;
    const int seg = y >> 3;
    const int n0 = (y & 7) * 128;
    const u16* Bt = seg == 0 ? Wq : seg == 1 ? Wk : Wv;
    const float* bias = seg == 0 ? bq : seg == 1 ? bk : bv;
    u16* out = seg == 0 ? Oq : seg == 1 ? Ok : Ov;
    gemm_tile<0, 128>(A, Bt, bias, out, m0, n0, C_EMB, C_EMB);
}

// O projection: grid (64, 8) of 64x128 tiles -> 512 blocks (2/CU), f32 out
__global__ __launch_bounds__(256) void gemm_o(const u16* __restrict__ A,
                                              const u16* __restrict__ Bt,
                                              const float* __restrict__ bias,
                                              float* __restrict__ out) {
    gemm_tile<1, 64>(A, Bt, bias, out, blockIdx.x * 64, blockIdx.y * 128, C_EMB, C_EMB);
}

// ---------------- windowed flash attention, staged pipeline ----------------
// 8 waves x 16 q-rows = 128 q-rows/block. Per 32-key chunk: K(32x64) staged
// row-major; V staged TRANSPOSED into Vs via scalar ds_writes. Double-buffered:
// next chunk's global->reg loads issued BEFORE computing current chunk from
// LDS; publish after compute; ONE barrier per chunk.
__global__ __launch_bounds__(512) void attn_win(const u16* __restrict__ Q,
                                                const u16* __restrict__ Kk,
                                                const u16* __restrict__ V,
                                                u16* __restrict__ Yo) {
    __shared__ u16 Ks[2][32][72];   // keys x dims, stride 72 (2-way banks on read)
    __shared__ u16 Vs[2][64][40];   // dims x keys, stride 40 (2-way banks on read)
    __shared__ u16 P[8][16][40];    // per-wave P^T

    const int tid = threadIdx.x;
    const int l = tid & 63, wid = tid >> 6;
    const int lr = l & 15, g = l >> 4;
    const int bx = blockIdx.x;
    const int L = (bx & 7) * 64 + (bx >> 3);   // 512 % 8 == 0 -> bijective
    const int h  = L >> 5;
    const int qs = (L & 31) * QBLK;
    const int qrow = qs + wid * 16 + lr;
    const float scale = 0.125f;

    const int krow = tid >> 3, kco = (tid & 7) * 8;          // tid<256
    const int t2 = tid - 256;
    const int vkr = t2 >> 3, vdc = (t2 & 7) * 8;             // tid>=256

    short8 qf[2];
#pragma unroll
    for (int u = 0; u < 2; ++u)
        qf[u] = *(const short8*)(Q + (size_t)qrow * C_EMB + h * HS + u * 32 + g * 8);

    f32x4 acc[4];
#pragma unroll
    for (int dt = 0; dt < 4; ++dt) acc[dt] = (f32x4){0.f, 0.f, 0.f, 0.f};
    float mrun = -1e30f, lsum = 0.f;

    int ks = qs - (WIN - 1);
    if (ks < 0) ks = 0; else ks &= ~31;
    const int nch = ((qs + QBLK) - ks) >> 5;
    const bool sinkch = (ks > 0);
    const int total = nch + (sinkch ? 1 : 0);

    {
        int kb0 = sinkch ? 0 : ks;
        if (tid < 256) {
            short8 r = *(const short8*)(Kk + (size_t)(kb0 + krow) * C_EMB + h * HS + kco);
            *(short8*)(&Ks[0][krow][kco]) = r;
        } else {
            short8 r = *(const short8*)(V + (size_t)(kb0 + vkr) * C_EMB + h * HS + vdc);
#pragma unroll
            for (int j = 0; j < 8; ++j) Vs[0][vdc + j][vkr] = (u16)r[j];
        }
    }
    __syncthreads();

    for (int ci = 0; ci < total; ++ci) {
        const int cur = ci & 1;
        const int kb = sinkch ? (ci == 0 ? 0 : ks + (ci - 1) * 32) : ks + ci * 32;
        const bool havenext = (ci + 1 < total);
        short8 nx;
        if (havenext) {
            int kbn = sinkch ? ks + ci * 32 : ks + (ci + 1) * 32;
            if (tid < 256) nx = *(const short8*)(Kk + (size_t)(kbn + krow) * C_EMB + h * HS + kco);
            else           nx = *(const short8*)(V  + (size_t)(kbn + vkr) * C_EMB + h * HS + vdc);
        }

        f32x4 s[2];
        __builtin_amdgcn_s_setprio(1);
#pragma unroll
        for (int u2 = 0; u2 < 2; ++u2) {
            short8 kf0 = *(const short8*)(&Ks[cur][u2 * 16 + lr][g * 8]);
            short8 kf1 = *(const short8*)(&Ks[cur][u2 * 16 + lr][32 + g * 8]);
            f32x4 z = (f32x4){0.f, 0.f, 0.f, 0.f};
            z = __builtin_amdgcn_mfma_f32_16x16x32_bf16(kf0, qf[0], z, 0, 0, 0);
            z = __builtin_amdgcn_mfma_f32_16x16x32_bf16(kf1, qf[1], z, 0, 0, 0);
            s[u2] = z;
        }
        __builtin_amdgcn_s_setprio(0);
        float pmax = -1e30f;
#pragma unroll
        for (int u2 = 0; u2 < 2; ++u2)
#pragma unroll
            for (int r = 0; r < 4; ++r) {
                int key = kb + u2 * 16 + g * 4 + r;
                bool ok = (key <= qrow) && ((key + (WIN - 1) >= qrow) || (key < SINKSZ));
                float sv = ok ? s[u2][r] * scale : -1e30f;
                s[u2][r] = sv;
                pmax = fmaxf(pmax, sv);
            }
        pmax = fmaxf(pmax, __shfl_xor(pmax, 16, 64));
        pmax = fmaxf(pmax, __shfl_xor(pmax, 32, 64));
        float mnew = fmaxf(mrun, pmax);
        float fsc = __expf(mrun - mnew);
        float psum = 0.f;
#pragma unroll
        for (int u2 = 0; u2 < 2; ++u2)
#pragma unroll
            for (int r = 0; r < 4; ++r) {
                float p = __expf(s[u2][r] - mnew);
                s[u2][r] = p;
                psum += p;
            }
        psum += __shfl_xor(psum, 16, 64);
        psum += __shfl_xor(psum, 32, 64);
        lsum = lsum * fsc + psum;
        mrun = mnew;
#pragma unroll
        for (int dt = 0; dt < 4; ++dt)
#pragma unroll
            for (int r = 0; r < 4; ++r) acc[dt][r] *= fsc;

#pragma unroll
        for (int u2 = 0; u2 < 2; ++u2) {
            short4v pw;
#pragma unroll
            for (int r = 0; r < 4; ++r) pw[r] = (short)f2bf(s[u2][r]);
            *(short4v*)(&P[wid][lr][u2 * 16 + g * 4]) = pw;
        }
        __builtin_amdgcn_s_setprio(1);
#pragma unroll
        for (int dt = 0; dt < 4; ++dt) {
            short8 vf = *(const short8*)(&Vs[cur][dt * 16 + lr][g * 8]);
            short8 pf = *(const short8*)(&P[wid][lr][g * 8]);
            acc[dt] = __builtin_amdgcn_mfma_f32_16x16x32_bf16(vf, pf, acc[dt], 0, 0, 0);
        }
        __builtin_amdgcn_s_setprio(0);

        if (havenext) {
            if (tid < 256) {
                *(short8*)(&Ks[cur ^ 1][krow][kco]) = nx;
            } else {
#pragma unroll
                for (int j = 0; j < 8; ++j) Vs[cur ^ 1][vdc + j][vkr] = (u16)nx[j];
            }
        }
        __syncthreads();
    }

    float inv = 1.f / lsum;
#pragma unroll
    for (int dt = 0; dt < 4; ++dt) {
        short4v w;
#pragma unroll
        for (int r = 0; r < 4; ++r) w[r] = (short)f2bf(acc[dt][r] * inv);
        *(short4v*)(Yo + (size_t)qrow * C_EMB + h * HS + dt * 16 + g * 4) = w;
    }
}

extern "C" void kernel_launch(void* const* d_in, const int* in_sizes, int n_in,
                              void* d_out, int out_size, void* d_ws, size_t ws_size,
                              hipStream_t stream) {
    const float* x   = (const float*)d_in[0];
    const float* q_w = (const float*)d_in[1];
    const float* q_b = (const float*)d_in[2];
    const float* k_w = (const float*)d_in[3];
    const float* k_b = (const float*)d_in[4];
    const float* v_w = (const float*)d_in[5];
    const float* v_b = (const float*)d_in[6];
    const float* o_w = (const float*)d_in[7];
    const float* o_b = (const float*)d_in[8];
    float* out = (float*)d_out;

    char* ws = (char*)d_ws;
    const size_t SZ_TC = (size_t)T_SEQ * C_EMB * 2;
    const size_t SZ_W  = (size_t)C_EMB * C_EMB * 2;
    u16* xb   = (u16*)(ws);                 ws += SZ_TC;
    u16* wqb  = (u16*)(ws);                 ws += SZ_W;
    u16* wkb  = (u16*)(ws);                 ws += SZ_W;
    u16* wvb  = (u16*)(ws);                 ws += SZ_W;
    u16* wob  = (u16*)(ws);                 ws += SZ_W;
    u16* qbuf = (u16*)(ws);                 ws += SZ_TC;
    u16* kbuf = (u16*)(ws);                 ws += SZ_TC;
    u16* vbuf = (u16*)(ws);                 ws += SZ_TC;
    u16* yatt = (u16*)(ws);                 ws += SZ_TC;

    const int nCvt = (T_SEQ * C_EMB + 4 * C_EMB * C_EMB) / 4;
    cvt_all<<<nCvt / 256, 256, 0, stream>>>(x, q_w, k_w, v_w, o_w,
                                            xb, wqb, wkb, wvb, wob);

    gemm_qkv<<<dim3(T_SEQ / 128, 24), 256, 0, stream>>>(xb, wqb, wkb, wvb,
                                                        q_b, k_b, v_b,
                                                        qbuf, kbuf, vbuf);

    attn_win<<<NH * (T_SEQ / QBLK), 512, 0, stream>>>(qbuf, kbuf, vbuf, yatt);

    gemm_o<<<dim3(T_SEQ / 64, C_EMB / 128), 256, 0, stream>>>(yatt, wob, o_b, out);
}

// Round 12
// 175.024 us; speedup vs baseline: 1.4044x; 1.0128x over previous
//
#include <hip/hip_runtime.h>
#include <hip/hip_bf16.h>
#include <cstdint>

#define T_SEQ 4096
#define C_EMB 1024
#define NH    16
#define HS    64
#define WIN   256
#define SINKSZ 4
#define QBLK  128
#define KVB   64

typedef short  short8  __attribute__((ext_vector_type(8)));
typedef short  short4v __attribute__((ext_vector_type(4)));
typedef float  f32x4   __attribute__((ext_vector_type(4)));
typedef unsigned short u16;

__device__ __forceinline__ u16 f2bf(float f) {
    uint32_t u = __builtin_bit_cast(uint32_t, f);
    u = u + 0x7fffu + ((u >> 16) & 1u);   // RNE
    return (u16)(u >> 16);
}

__device__ __forceinline__ void gload_lds16(const void* g, void* l) {
    __builtin_amdgcn_global_load_lds(
        (const __attribute__((address_space(1))) uint32_t*)g,
        (__attribute__((address_space(3))) uint32_t*)l, 16, 0, 0);
}

// ---------------- fused f32 -> bf16 convert (x + 4 weights, 1 launch) ----------------
__global__ __launch_bounds__(256) void cvt_all(const float* __restrict__ x,
                                               const float* __restrict__ w0,
                                               const float* __restrict__ w1,
                                               const float* __restrict__ w2,
                                               const float* __restrict__ w3,
                                               u16* __restrict__ xb,
                                               u16* __restrict__ o0,
                                               u16* __restrict__ o1,
                                               u16* __restrict__ o2,
                                               u16* __restrict__ o3) {
    const int NX = (T_SEQ * C_EMB) / 4;    // 1048576 float4
    const int NW = (C_EMB * C_EMB) / 4;    // 262144 float4
    int i = blockIdx.x * 256 + threadIdx.x;
    const float* src; u16* dst; int off;
    if (i < NX) { src = x; dst = xb; off = i; }
    else {
        int j = i - NX;
        int w = j >> 18;                    // /262144
        off = j & (NW - 1);
        src = w == 0 ? w0 : w == 1 ? w1 : w == 2 ? w2 : w3;
        dst = w == 0 ? o0 : w == 1 ? o1 : w == 2 ? o2 : o3;
    }
    float4 v = ((const float4*)src)[off];
    ushort4 o;
    o.x = f2bf(v.x); o.y = f2bf(v.y); o.z = f2bf(v.z); o.w = f2bf(v.w);
    ((ushort4*)dst)[off] = o;
}

// ---------------- 2-phase double-buffered bf16 GEMM core ----------------
template<int OUT_F32, int BM>
__device__ __forceinline__ void gemm_tile(const u16* __restrict__ A,
                                          const u16* __restrict__ Bt,
                                          const float* __restrict__ bias,
                                          void* __restrict__ Cout,
                                          int m0, int n0, int N, int K) {
    constexpr int MR = BM / 32;            // m-fragments per wave
    __shared__ u16 As[2][BM * 32];
    __shared__ u16 Bs[2][128 * 32];
    const int tid = threadIdx.x;
    const int l = tid & 63, wid = tid >> 6;
    const int lr = l & 15, g = l >> 4;
    const int wm = (wid >> 1) * (BM / 2), wn = (wid & 1) * 64;

    const int rowA = tid >> 2, colA = (tid & 3) << 3;
    const u16* gA0 = A  + (size_t)(m0 + rowA) * K + colA;
    const u16* gA1 = A  + (size_t)(m0 + (BM == 128 ? 64 : 0) + rowA) * K + colA;
    const u16* gB0 = Bt + (size_t)(n0 + rowA) * K + colA;
    const u16* gB1 = Bt + (size_t)(n0 + 64 + rowA) * K + colA;
    const int eo0 = tid * 8, eo1 = (256 + tid) * 8;

    f32x4 acc[MR][4];
#pragma unroll
    for (int m = 0; m < MR; ++m)
#pragma unroll
        for (int n = 0; n < 4; ++n)
            acc[m][n] = (f32x4){0.f, 0.f, 0.f, 0.f};

    gload_lds16(gA0, &As[0][eo0]);
    if constexpr (BM == 128) gload_lds16(gA1, &As[0][eo1]);
    gload_lds16(gB0, &Bs[0][eo0]);
    gload_lds16(gB1, &Bs[0][eo1]);
    __syncthreads();

    const int nk = K >> 5;
    for (int t = 0; t < nk; ++t) {
        const int cur = t & 1;
        if (t + 1 < nk) {
            int ko = (t + 1) << 5;
            gload_lds16(gA0 + ko, &As[cur ^ 1][eo0]);
            if constexpr (BM == 128) gload_lds16(gA1 + ko, &As[cur ^ 1][eo1]);
            gload_lds16(gB0 + ko, &Bs[cur ^ 1][eo0]);
            gload_lds16(gB1 + ko, &Bs[cur ^ 1][eo1]);
        }
        short8 af[MR], bf[4];
#pragma unroll
        for (int m = 0; m < MR; ++m)
            af[m] = *(const short8*)(&As[cur][(wm + m * 16 + lr) * 32 + g * 8]);
#pragma unroll
        for (int n = 0; n < 4; ++n)
            bf[n] = *(const short8*)(&Bs[cur][(wn + n * 16 + lr) * 32 + g * 8]);
#pragma unroll
        for (int m = 0; m < MR; ++m)
#pragma unroll
            for (int n = 0; n < 4; ++n)
                acc[m][n] = __builtin_amdgcn_mfma_f32_16x16x32_bf16(af[m], bf[n], acc[m][n], 0, 0, 0);
        __syncthreads();
    }

#pragma unroll
    for (int n = 0; n < 4; ++n) {
        int col = n0 + wn + n * 16 + lr;
        float b = bias[col];
#pragma unroll
        for (int m = 0; m < MR; ++m) {
            int rowb = m0 + wm + m * 16 + g * 4;
#pragma unroll
            for (int r = 0; r < 4; ++r) {
                float v = acc[m][n][r] + b;
                if (OUT_F32) ((float*)Cout)[(size_t)(rowb + r) * N + col] = v;
                else         ((u16*)Cout)[(size_t)(rowb + r) * N + col] = f2bf(v);
            }
        }
    }
}

// Fused QKV projection: grid (32, 24), XCD-grouped tile order:
// HW round-robins linear blockIdx over 8 XCDs; remap so each XCD gets 96
// CONSECUTIVE logical tiles (A-panels reused within one XCD's L2).
__global__ __launch_bounds__(256) void gemm_qkv(const u16* __restrict__ A,
                                                const u16* __restrict__ Wq,
                                                const u16* __restrict__ Wk,
                                                const u16* __restrict__ Wv,
                                                const float* __restrict__ bq,
                                                const float* __restrict__ bk,
                                                const float* __restrict__ bv,
                                                u16* __restrict__ Oq,
                                                u16* __restrict__ Ok,
                                                u16* __restrict__ Ov) {
    const int lid = blockIdx.y * gridDim.x + blockIdx.x;   // 768 blocks, 768%8==0
    const int logical = (lid & 7) * 96 + (lid >> 3);
    const int m0 = (logical & 31) * 128;
    const int y  = logical >> 5;
    const int seg = y >> 3;
    const int n0 = (y & 7) * 128;
    const u16* Bt = seg == 0 ? Wq : seg == 1 ? Wk : Wv;
    const float* bias = seg == 0 ? bq : seg == 1 ? bk : bv;
    u16* out = seg == 0 ? Oq : seg == 1 ? Ok : Ov;
    gemm_tile<0, 128>(A, Bt, bias, out, m0, n0, C_EMB, C_EMB);
}

// O projection: grid (64, 8) of 64x128 tiles, XCD-grouped, f32 out
__global__ __launch_bounds__(256) void gemm_o(const u16* __restrict__ A,
                                              const u16* __restrict__ Bt,
                                              const float* __restrict__ bias,
                                              float* __restrict__ out) {
    const int lid = blockIdx.y * gridDim.x + blockIdx.x;   // 512 blocks
    const int logical = (lid & 7) * 64 + (lid >> 3);
    const int m0 = (logical & 63) * 64;
    const int n0 = (logical >> 6) * 128;
    gemm_tile<1, 64>(A, Bt, bias, out, m0, n0, C_EMB, C_EMB);
}

// ---------------- windowed flash attention, staged pipeline, KVB=64 ----------------
// 8 waves x 16 q-rows. Per 64-key chunk: K(64x64) staged row-major (stride 72);
// V staged TRANSPOSED into Vs[64][64] with XOR-8-block swizzle
// col ^= (((row^(row>>3))&7)<<3)  -> both transpose scatter-writes and b128
// reads hit the 8-slot/bank minimum (conflict-free; padding can't fix writes).
// KVB 32->64 halves barriers + softmax serial passes (13 -> <=7 chunks).
__global__ __launch_bounds__(512) void attn_win(const u16* __restrict__ Q,
                                                const u16* __restrict__ Kk,
                                                const u16* __restrict__ V,
                                                u16* __restrict__ Yo) {
    __shared__ u16 Ks[2][KVB][72];
    __shared__ u16 Vs[2][64][64];
    __shared__ u16 P[8][16][72];

    const int tid = threadIdx.x;
    const int l = tid & 63, wid = tid >> 6;
    const int lr = l & 15, g = l >> 4;
    const int bx = blockIdx.x;
    const int L = (bx & 7) * 64 + (bx >> 3);   // 512 % 8 == 0 -> bijective
    const int h  = L >> 5;
    const int qs = (L & 31) * QBLK;
    const int qrow = qs + wid * 16 + lr;
    const float scale = 0.125f;

    // staging roles (wave-uniform): waves 0-3 K, waves 4-7 V(transposed)
    const int srow = (tid & 255) >> 3;         // 0..31 (rows srow and srow+32)
    const int sco  = (tid & 7) * 8;            // col base

    short8 qf[2];
#pragma unroll
    for (int u = 0; u < 2; ++u)
        qf[u] = *(const short8*)(Q + (size_t)qrow * C_EMB + h * HS + u * 32 + g * 8);

    f32x4 acc[4];
#pragma unroll
    for (int dt = 0; dt < 4; ++dt) acc[dt] = (f32x4){0.f, 0.f, 0.f, 0.f};
    float mrun = -1e30f, lsum = 0.f;

    int ks0 = qs - (WIN - 1);
    if (ks0 < 0) ks0 = 0; else ks0 &= ~(KVB - 1);
    const int nch = ((qs + QBLK) - ks0) >> 6;
    const bool sinkch = (ks0 > 0);
    const int total = nch + (sinkch ? 1 : 0);

    // V transpose-scatter into swizzled Vs
    auto vstore = [&](int buf, short8 r0, short8 r1) {
#pragma unroll
        for (int j = 0; j < 8; ++j) {
            int row = sco + j;
            int fr = ((row ^ (row >> 3)) & 7) << 3;
            Vs[buf][row][srow ^ fr] = (u16)r0[j];
            Vs[buf][row][(srow + 32) ^ fr] = (u16)r1[j];
        }
    };

    // prologue: stage chunk 0
    {
        int kb0 = sinkch ? 0 : ks0;
        if (tid < 256) {
            short8 r0 = *(const short8*)(Kk + (size_t)(kb0 + srow) * C_EMB + h * HS + sco);
            short8 r1 = *(const short8*)(Kk + (size_t)(kb0 + srow + 32) * C_EMB + h * HS + sco);
            *(short8*)(&Ks[0][srow][sco]) = r0;
            *(short8*)(&Ks[0][srow + 32][sco]) = r1;
        } else {
            short8 r0 = *(const short8*)(V + (size_t)(kb0 + srow) * C_EMB + h * HS + sco);
            short8 r1 = *(const short8*)(V + (size_t)(kb0 + srow + 32) * C_EMB + h * HS + sco);
            vstore(0, r0, r1);
        }
    }
    __syncthreads();

    for (int ci = 0; ci < total; ++ci) {
        const int cur = ci & 1;
        const int kb = sinkch ? (ci == 0 ? 0 : ks0 + (ci - 1) * KVB) : ks0 + ci * KVB;
        const bool havenext = (ci + 1 < total);
        short8 nx0, nx1;
        if (havenext) {
            int kbn = sinkch ? ks0 + ci * KVB : ks0 + (ci + 1) * KVB;
            const u16* base = (tid < 256) ? Kk : V;
            nx0 = *(const short8*)(base + (size_t)(kbn + srow) * C_EMB + h * HS + sco);
            nx1 = *(const short8*)(base + (size_t)(kbn + srow + 32) * C_EMB + h * HS + sco);
        }

        // ---- QK^T for 64 keys (4 sub-chunks of 16) ----
        f32x4 s[4];
        __builtin_amdgcn_s_setprio(1);
#pragma unroll
        for (int u2 = 0; u2 < 4; ++u2) {
            short8 kf0 = *(const short8*)(&Ks[cur][u2 * 16 + lr][g * 8]);
            short8 kf1 = *(const short8*)(&Ks[cur][u2 * 16 + lr][32 + g * 8]);
            f32x4 z = (f32x4){0.f, 0.f, 0.f, 0.f};
            z = __builtin_amdgcn_mfma_f32_16x16x32_bf16(kf0, qf[0], z, 0, 0, 0);
            z = __builtin_amdgcn_mfma_f32_16x16x32_bf16(kf1, qf[1], z, 0, 0, 0);
            s[u2] = z;
        }
        __builtin_amdgcn_s_setprio(0);

        float pmax = -1e30f;
#pragma unroll
        for (int u2 = 0; u2 < 4; ++u2)
#pragma unroll
            for (int r = 0; r < 4; ++r) {
                int key = kb + u2 * 16 + g * 4 + r;
                bool ok = (key <= qrow) && ((key + (WIN - 1) >= qrow) || (key < SINKSZ));
                float sv = ok ? s[u2][r] * scale : -1e30f;
                s[u2][r] = sv;
                pmax = fmaxf(pmax, sv);
            }
        pmax = fmaxf(pmax, __shfl_xor(pmax, 16, 64));
        pmax = fmaxf(pmax, __shfl_xor(pmax, 32, 64));
        float mnew = fmaxf(mrun, pmax);
        float fsc = __expf(mrun - mnew);
        float psum = 0.f;
#pragma unroll
        for (int u2 = 0; u2 < 4; ++u2)
#pragma unroll
            for (int r = 0; r < 4; ++r) {
                float p = __expf(s[u2][r] - mnew);
                s[u2][r] = p;
                psum += p;
            }
        psum += __shfl_xor(psum, 16, 64);
        psum += __shfl_xor(psum, 32, 64);
        lsum = lsum * fsc + psum;
        mrun = mnew;
#pragma unroll
        for (int dt = 0; dt < 4; ++dt)
#pragma unroll
            for (int r = 0; r < 4; ++r) acc[dt][r] *= fsc;

        // P^T (16 q x 64 keys) bf16
#pragma unroll
        for (int u2 = 0; u2 < 4; ++u2) {
            short4v pw;
#pragma unroll
            for (int r = 0; r < 4; ++r) pw[r] = (short)f2bf(s[u2][r]);
            *(short4v*)(&P[wid][lr][u2 * 16 + g * 4]) = pw;
        }

        // PV: acc[dt] += V^T[d, k] . P^T[k, q] over 64 keys (2 k-slices)
        __builtin_amdgcn_s_setprio(1);
#pragma unroll
        for (int dt = 0; dt < 4; ++dt) {
            int row = dt * 16 + lr;
            int fr = ((row ^ (row >> 3)) & 7) << 3;
#pragma unroll
            for (int ksl = 0; ksl < 2; ++ksl) {
                short8 vf = *(const short8*)(&Vs[cur][row][(ksl * 32 + g * 8) ^ fr]);
                short8 pf = *(const short8*)(&P[wid][lr][ksl * 32 + g * 8]);
                acc[dt] = __builtin_amdgcn_mfma_f32_16x16x32_bf16(vf, pf, acc[dt], 0, 0, 0);
            }
        }
        __builtin_amdgcn_s_setprio(0);

        // publish next chunk
        if (havenext) {
            if (tid < 256) {
                *(short8*)(&Ks[cur ^ 1][srow][sco]) = nx0;
                *(short8*)(&Ks[cur ^ 1][srow + 32][sco]) = nx1;
            } else {
                vstore(cur ^ 1, nx0, nx1);
            }
        }
        __syncthreads();
    }

    float inv = 1.f / lsum;
#pragma unroll
    for (int dt = 0; dt < 4; ++dt) {
        short4v w;
#pragma unroll
        for (int r = 0; r < 4; ++r) w[r] = (short)f2bf(acc[dt][r] * inv);
        *(short4v*)(Yo + (size_t)qrow * C_EMB + h * HS + dt * 16 + g * 4) = w;
    }
}

extern "C" void kernel_launch(void* const* d_in, const int* in_sizes, int n_in,
                              void* d_out, int out_size, void* d_ws, size_t ws_size,
                              hipStream_t stream) {
    const float* x   = (const float*)d_in[0];
    const float* q_w = (const float*)d_in[1];
    const float* q_b = (const float*)d_in[2];
    const float* k_w = (const float*)d_in[3];
    const float* k_b = (const float*)d_in[4];
    const float* v_w = (const float*)d_in[5];
    const float* v_b = (const float*)d_in[6];
    const float* o_w = (const float*)d_in[7];
    const float* o_b = (const float*)d_in[8];
    float* out = (float*)d_out;

    char* ws = (char*)d_ws;
    const size_t SZ_TC = (size_t)T_SEQ * C_EMB * 2;
    const size_t SZ_W  = (size_t)C_EMB * C_EMB * 2;
    u16* xb   = (u16*)(ws);                 ws += SZ_TC;
    u16* wqb  = (u16*)(ws);                 ws += SZ_W;
    u16* wkb  = (u16*)(ws);                 ws += SZ_W;
    u16* wvb  = (u16*)(ws);                 ws += SZ_W;
    u16* wob  = (u16*)(ws);                 ws += SZ_W;
    u16* qbuf = (u16*)(ws);                 ws += SZ_TC;
    u16* kbuf = (u16*)(ws);                 ws += SZ_TC;
    u16* vbuf = (u16*)(ws);                 ws += SZ_TC;
    u16* yatt = (u16*)(ws);                 ws += SZ_TC;

    const int nCvt = (T_SEQ * C_EMB + 4 * C_EMB * C_EMB) / 4;
    cvt_all<<<nCvt / 256, 256, 0, stream>>>(x, q_w, k_w, v_w, o_w,
                                            xb, wqb, wkb, wvb, wob);

    gemm_qkv<<<dim3(T_SEQ / 128, 24), 256, 0, stream>>>(xb, wqb, wkb, wvb,
                                                        q_b, k_b, v_b,
                                                        qbuf, kbuf, vbuf);

    attn_win<<<NH * (T_SEQ / QBLK), 512, 0, stream>>>(qbuf, kbuf, vbuf, yatt);

    gemm_o<<<dim3(T_SEQ / 64, C_EMB / 128), 256, 0, stream>>>(yatt, wob, o_b, out);
}